// Round 2
// baseline (269.541 us; speedup 1.0000x reference)
//
#include <hip/hip_runtime.h>
#include <cstdint>

typedef __bf16 bf16x8 __attribute__((ext_vector_type(8)));
typedef float f32x4 __attribute__((ext_vector_type(4)));
typedef uint32_t u32x4 __attribute__((ext_vector_type(4)));
typedef unsigned short u16;

#define B_ 4
#define T_ 2048
#define D_ 1024
#define H_ 16
#define HD_ 64
#define M_ (B_*T_)
// attention scale 1/8 with log2(e) folded in, applied in Q epilogue -> softmax uses exp2
#define QSCALE 0.1803368801111204f

__device__ __forceinline__ u16 f2bf(float f) {
  union { float f; uint32_t u; } x; x.f = f;
  uint32_t u = x.u;
  uint32_t r = (u + 0x7FFFu + ((u >> 16) & 1u)) >> 16;
  return (u16)r;
}

// fast pack: 2 fp32 -> packed bf16x2 via v_perm_b32 (2 adds + 1 perm); p>=0 here.
__device__ __forceinline__ uint32_t pkbf(float a, float b) {
  union { float f; uint32_t u; } x, y; x.f = a; y.f = b;
  uint32_t t0 = x.u + 0x8000u, t1 = y.u + 0x8000u;
  return __builtin_amdgcn_perm(t1, t0, 0x07060302u);  // [t0.b2,t0.b3,t1.b2,t1.b3]
}

__device__ __forceinline__ bf16x8 ld8(const u16* p) {
  return *(const bf16x8*)p;
}

// async global->LDS, 16B per lane; lds ptr must be wave-uniform base (HW adds lane*16)
__device__ __forceinline__ void gl_lds16(const u16* g, u16* l) {
  __builtin_amdgcn_global_load_lds(
      (__attribute__((address_space(1))) void*)(g),
      (__attribute__((address_space(3))) void*)(l), 16, 0, 0);
}

// Fused fp32->bf16 convert of x + 4 weight matrices.
__global__ void cvt_all(const float* __restrict__ x, const float* __restrict__ wq,
                        const float* __restrict__ wk, const float* __restrict__ wv,
                        const float* __restrict__ wo,
                        u16* __restrict__ xb, u16* __restrict__ wqb, u16* __restrict__ wkb,
                        u16* __restrict__ wvb, u16* __restrict__ wob) {
  const long NX = (long)M_ * D_;
  long i = ((long)blockIdx.x * 256 + threadIdx.x) * 4;
  const float* s; u16* d; long j;
  if (i < NX) { s = x; d = xb; j = i; }
  else {
    long r = i - NX; int seg = (int)(r >> 20); j = r & ((1 << 20) - 1);
    s = seg == 0 ? wq : seg == 1 ? wk : seg == 2 ? wv : wo;
    d = seg == 0 ? wqb : seg == 1 ? wkb : seg == 2 ? wvb : wob;
  }
  float4 v = *(const float4*)(s + j);
  ushort4 o;
  o.x = f2bf(v.x); o.y = f2bf(v.y); o.z = f2bf(v.z); o.w = f2bf(v.w);
  *(ushort4*)(d + j) = o;
}

// ---------------------------------------------------------------------------
// gemm_qkv v3: 256x128 tile, 768 blocks = EXACTLY 3 uniform rounds on 256 CUs
// (fixes round-1's 1.5-round tail = hard 75% util cap at 384 blocks).
//   512 thr = 8 waves, grid 4(M) x 2(N), per-wave output 64x64 (acc[4][4]).
//   LDS: TRIPLE buffer, each (A 256 rows | B 128 rows) x 64 k bf16 = 48 KiB,
//   total 144 KiB. Stage of tile kt+2 targets buf (kt+2)%3 -- never the live
//   or next buffer, so the write-after-read ledger is trivially safe.
//   Per K-tile: 2 phases of 16 MFMA/wave (mi-halves); ph0: 12 ds_read + 3
//   stage units, ph1: 4 ds_read + 3 stage units; counted vmcnt(6) once per
//   tile (1.5-2 tiles of load lead; never drained to 0 until the end).
//   T2 swizzle kept (proven: bank conflicts 6.8M -> 131K): LDS[r][c16] holds
//   G[r][c16 ^ (r&7)] via pre-swizzled global source; reads XOR the same.
//   T1: XCD-chunked block swizzle (768 % 8 == 0, bijective); each XCD gets 4
//   contiguous m-rows -> A-panel 2MB resident in its 4MB L2.
// ---------------------------------------------------------------------------

template <int PH>
__device__ __forceinline__ void ldA_ph(bf16x8 (&af)[2][2], const u16* buf,
                                       int wr, int lanem, int quad) {
#pragma unroll
  for (int mi = 0; mi < 2; ++mi)
#pragma unroll
    for (int ks = 0; ks < 2; ++ks) {
      int row = wr * 64 + (PH * 2 + mi) * 16 + lanem;
      int off = row * 64 + ((ks * 32 + quad * 8) ^ ((lanem & 7) << 3));  // u16 units
      af[mi][ks] = ld8(buf + off);
    }
}

__device__ __forceinline__ void ldB_all(bf16x8 (&bfr)[4][2], const u16* buf,
                                        int wc, int lanem, int quad) {
#pragma unroll
  for (int nj = 0; nj < 4; ++nj)
#pragma unroll
    for (int ks = 0; ks < 2; ++ks) {
      int row = 256 + wc * 64 + nj * 16 + lanem;
      int off = row * 64 + ((ks * 32 + quad * 8) ^ ((lanem & 7) << 3));
      bfr[nj][ks] = ld8(buf + off);
    }
}

template <int PH>
__device__ __forceinline__ void mfmaPH(f32x4 (&acc)[4][4], const bf16x8 (&af)[2][2],
                                       const bf16x8 (&bfr)[4][2]) {
#pragma unroll
  for (int mi = 0; mi < 2; ++mi)
#pragma unroll
    for (int nj = 0; nj < 4; ++nj)
#pragma unroll
      for (int ks = 0; ks < 2; ++ks)
        acc[PH * 2 + mi][nj] = __builtin_amdgcn_mfma_f32_16x16x32_bf16(
            af[mi][ks], bfr[nj][ks], acc[PH * 2 + mi][nj], 0, 0, 0);
}

#define PH_PRE()                                        \
  __builtin_amdgcn_s_barrier();                         \
  asm volatile("s_waitcnt lgkmcnt(0)" ::: "memory");    \
  __builtin_amdgcn_sched_barrier(0);                    \
  __builtin_amdgcn_s_setprio(1)

#define PH_POST()                                       \
  __builtin_amdgcn_s_setprio(0);                        \
  __builtin_amdgcn_s_barrier()

__global__ __launch_bounds__(512, 2)
void gemm_qkv(const u16* __restrict__ A, const u16* __restrict__ Bw,
              const float* __restrict__ bq, const float* __restrict__ bk,
              const float* __restrict__ bv,
              u16* __restrict__ qb, u16* __restrict__ kb, u16* __restrict__ vtb) {
  __shared__ union {
    u16 S[3][384][64];   // 3 bufs x (A rows 0..255 | B rows 256..383) x 64k = 144 KiB
    u16 C[256 * 136];    // epilogue bounce: Q/K [256][136]; V uses [128][264]
  } sm;

  const int tid = threadIdx.x;
  const int wv = tid >> 6, lane = tid & 63;
  const int lanem = lane & 15, quad = lane >> 4;
  const int wr = wv >> 1, wc = wv & 1;   // wave grid 4 (M) x 2 (N)

  // XCD-chunked bijective swizzle: 96 consecutive tiles (= 4 m-rows) per XCD
  const int l = ((int)blockIdx.x & 7) * 96 + ((int)blockIdx.x >> 3);
  const int n0 = (l % 24) * 128, m0 = (l / 24) * 256;

  // per-lane pre-swizzled global source (T2 involution, row&7 == grow)
  const int grow = lane >> 3;
  const int gcol = (((lane & 7) ^ grow) * 8);

  // stage unit u: u<4 -> A rows [u*64,u*64+64); u>=4 -> B rows [(u-4)*64, ...)
  auto stage = [&](u16* bufbase, int u, int k0) {
    const u16* src = (u < 4)
        ? A  + (size_t)(m0 + u * 64 + wv * 8 + grow) * D_ + k0 + gcol
        : Bw + (size_t)(n0 + (u - 4) * 64 + wv * 8 + grow) * D_ + k0 + gcol;
    gl_lds16(src, bufbase + (u * 64 + wv * 8) * 64);
  };

  f32x4 acc[4][4];
#pragma unroll
  for (int a = 0; a < 4; ++a)
#pragma unroll
    for (int b = 0; b < 4; ++b) acc[a][b] = (f32x4){0.f, 0.f, 0.f, 0.f};

  bf16x8 af[2][2];
  bf16x8 bfr[4][2];

  u16* p0 = &sm.S[0][0][0];   // tile kt (read)
  u16* p1 = &sm.S[1][0][0];   // tile kt+1 (landing)
  u16* p2 = &sm.S[2][0][0];   // tile kt+2 (stage target)

  // prologue: tile0 -> buf0, tile1 -> buf1; wait tile0 landed (6 remain).
#pragma unroll
  for (int u = 0; u < 6; ++u) stage(p0, u, 0);
#pragma unroll
  for (int u = 0; u < 6; ++u) stage(p1, u, 64);
  asm volatile("s_waitcnt vmcnt(6)" ::: "memory");
  __builtin_amdgcn_s_barrier();

  for (int kt = 0; kt < 16; ++kt) {
    const int k2 = (kt + 2) << 6;

    // ---- phase 0: mi-half 0 (12 ds_read, 3 stage units)
    ldA_ph<0>(af, p0, wr, lanem, quad);
    ldB_all(bfr, p0, wc, lanem, quad);
    if (kt < 14) { stage(p2, 0, k2); stage(p2, 1, k2); stage(p2, 2, k2); }
    PH_PRE();
    mfmaPH<0>(acc, af, bfr);
    PH_POST();

    // ---- phase 1: mi-half 1 (4 ds_read, 3 stage units), per-tile vmcnt
    ldA_ph<1>(af, p0, wr, lanem, quad);
    if (kt < 14) { stage(p2, 3, k2); stage(p2, 4, k2); stage(p2, 5, k2); }
    __builtin_amdgcn_s_barrier();
    asm volatile("s_waitcnt lgkmcnt(0)" ::: "memory");
    __builtin_amdgcn_sched_barrier(0);
    __builtin_amdgcn_s_setprio(1);
    mfmaPH<1>(acc, af, bfr);
    __builtin_amdgcn_s_setprio(0);
    if (kt < 14)       asm volatile("s_waitcnt vmcnt(6)" ::: "memory");
    else if (kt == 14) asm volatile("s_waitcnt vmcnt(0)" ::: "memory");
    __builtin_amdgcn_s_barrier();

    u16* t = p0; p0 = p1; p1 = p2; p2 = t;
  }

  // ---- epilogue: bounce through the (now free) LDS union
  const int seg = n0 >> 10, n0l = n0 & 1023;   // BN=128 divides 1024: no crossing
  const int bb = m0 >> 11, tl0 = m0 & (T_ - 1);

  if (seg == 2) {
    // V: transposed bounce [128 ncol][264 (256 t + pad)], single pass
    __syncthreads();
#pragma unroll
    for (int a = 0; a < 4; ++a)
#pragma unroll
      for (int nj = 0; nj < 4; ++nj) {
        int ncol = wc * 64 + nj * 16 + lanem;
        float bvv = bv[n0l + ncol];
        int mb = wr * 64 + a * 16 + quad * 4;
        ushort4 w4;
        w4.x = f2bf(acc[a][nj][0] + bvv);
        w4.y = f2bf(acc[a][nj][1] + bvv);
        w4.z = f2bf(acc[a][nj][2] + bvv);
        w4.w = f2bf(acc[a][nj][3] + bvv);
        *(ushort4*)&sm.C[ncol * 264 + mb] = w4;
      }
    __syncthreads();
#pragma unroll
    for (int it = 0; it < 8; ++it) {
      int chunk = it * 512 + tid;
      int nrow = chunk >> 5, c8 = chunk & 31;
      int gnl = n0l + nrow;
      int hh = gnl >> 6, hd = gnl & 63;
      *(uint4*)&vtb[(((size_t)bb * H_ + hh) * HD_ + hd) * T_ + tl0 + c8 * 8] =
          *(const uint4*)&sm.C[nrow * 264 + c8 * 8];
    }
  } else {
    // Q/K: [256 t][136 (128 hd-cols + pad)] bounce, single pass
    const float* bias = seg == 0 ? bq : bk;
    u16* out = seg == 0 ? qb : kb;
    const float sc = seg == 0 ? QSCALE : 1.0f;
    __syncthreads();
#pragma unroll
    for (int a = 0; a < 4; ++a)
#pragma unroll
      for (int nj = 0; nj < 4; ++nj) {
        int col = wc * 64 + nj * 16 + lanem;
        float bvv = bias[n0l + col];
        int r = wr * 64 + a * 16 + quad * 4;
#pragma unroll
        for (int i = 0; i < 4; ++i)
          sm.C[(r + i) * 136 + col] = f2bf((acc[a][nj][i] + bvv) * sc);
      }
    __syncthreads();
#pragma unroll
    for (int it = 0; it < 8; ++it) {
      int chunk = it * 512 + tid;
      int row = chunk >> 4, c8 = chunk & 15;
      int col0 = c8 * 8;
      int hh = (n0l + col0) >> 6, hd = col0 & 63;
      int t = tl0 + row;
      *(uint4*)&out[(((size_t)bb * H_ + hh) * T_ + t) * HD_ + hd] =
          *(const uint4*)&sm.C[row * 136 + col0];
    }
  }
}

// Output projection: C = ob(8192x1024) * wo(1024x1024)^T + bo, fp32 out.
// 128x128 tile, BK=64, (256,3). Grid 8x64 = 512 blocks -> 2/CU, uniform.
__global__ __launch_bounds__(256, 3)
void gemm_wo(const u16* __restrict__ A, const u16* __restrict__ Bw,
             const float* __restrict__ bias, float* __restrict__ Co) {
  __shared__ u16 S[2][2][4096];   // [matrix][panel ks][128*32]
  int tid = threadIdx.x;
  int n0 = blockIdx.x * 128, m0 = blockIdx.y * 128;
  int wv = tid >> 6, lane = tid & 63, lanem = lane & 15, quad = lane >> 4;
  int wm = (wv >> 1) * 64, wn = (wv & 1) * 64;

  int rA = wv * 16 + (lane >> 2);
  int cc = (lane & 3) * 8;
  const u16* Ab = A + (size_t)(m0 + rA) * D_ + cc;
  const u16* Bb = Bw + (size_t)(n0 + rA) * D_ + cc;

  f32x4 acc[4][4];
#pragma unroll
  for (int mi = 0; mi < 4; ++mi)
#pragma unroll
    for (int ni = 0; ni < 4; ++ni)
      acc[mi][ni] = (f32x4){0.f, 0.f, 0.f, 0.f};

  for (int kt = 0; kt < 16; ++kt) {
    int k0 = kt * 64;
    __syncthreads();
#pragma unroll
    for (int ks = 0; ks < 2; ++ks)
#pragma unroll
      for (int j = 0; j < 2; ++j) {
        gl_lds16(Ab + k0 + ks * 32 + (size_t)j * 64 * D_,
                 &S[0][ks][(j * 256 + wv * 64) * 8]);
        gl_lds16(Bb + k0 + ks * 32 + (size_t)j * 64 * D_,
                 &S[1][ks][(j * 256 + wv * 64) * 8]);
      }
    __syncthreads();
#pragma unroll
    for (int ks = 0; ks < 2; ++ks) {
      bf16x8 af[4], bfr[4];
#pragma unroll
      for (int mi = 0; mi < 4; ++mi)
        af[mi] = ld8(&S[0][ks][(wm + mi * 16 + lanem) * 32 + quad * 8]);
#pragma unroll
      for (int ni = 0; ni < 4; ++ni)
        bfr[ni] = ld8(&S[1][ks][(wn + ni * 16 + lanem) * 32 + quad * 8]);
#pragma unroll
      for (int mi = 0; mi < 4; ++mi)
#pragma unroll
        for (int ni = 0; ni < 4; ++ni)
          acc[mi][ni] = __builtin_amdgcn_mfma_f32_16x16x32_bf16(af[mi], bfr[ni], acc[mi][ni], 0, 0, 0);
    }
  }

#pragma unroll
  for (int ni = 0; ni < 4; ++ni) {
    int gn = n0 + wn + ni * 16 + lanem;
    float bvv = bias[gn];
#pragma unroll
    for (int mi = 0; mi < 4; ++mi)
#pragma unroll
      for (int i = 0; i < 4; ++i) {
        int gm = m0 + wm + mi * 16 + quad * 4 + i;
        Co[(size_t)gm * D_ + gn] = acc[mi][ni][i] + bvv;
      }
  }
}

// Flash attention v4r2: round-10 core + reassociated lsum (4 partial accumulators
// per mi — breaks the 16-long serial v_add_f32 chain into 4x4; sum of positives,
// order-free). Exact-balance qt swizzle + hardened barrier retained.
__global__ __launch_bounds__(256, 4)
void flash4(const u16* __restrict__ qb, const u16* __restrict__ kb,
            const u16* __restrict__ vtb, u16* __restrict__ ob) {
  __shared__ u16 Ks[2][2][64][32];   // [buf][dhalf][slot][d32]  (slot = permuted key)
  __shared__ u16 Vs[2][2][64][32];   // [buf][shalf][hd][s32]
  int tid = threadIdx.x, wv = tid >> 6, lane = tid & 63;
  int lanem = lane & 15, quad = lane >> 4;
  int h = blockIdx.y, b = blockIdx.z;
  int z = (int)blockIdx.z;
  int qt = ((int)blockIdx.x ^ ((z & 1) * 15) ^ ((z >> 1) * 3)) & 15;
  size_t bh = (size_t)b * H_ + h;
  int qrow0 = qt * 128 + wv * 32;
  const u16* Qg = qb + (bh * T_ + qrow0) * HD_;
  const u16* Kg = kb + bh * T_ * HD_;
  const u16* Vg = vtb + bh * HD_ * T_;

  // staging: chunk tid -> slot=tid>>2, col8=tid&3; K source row is the permuted key
  int slot = tid >> 2, r = slot & 15;
  int key = (slot >> 5) * 32 + (r >> 2) * 8 + ((slot >> 4) & 1) * 4 + (r & 3);
  const u16* gK = Kg + (size_t)key * HD_ + (tid & 3) * 8;
  const u16* gV = Vg + (size_t)slot * T_ + (tid & 3) * 8;

  // Q as B-operand fragments (B[n=q=lanem][k=d=quad*8+j])
  bf16x8 bq[2][2];
#pragma unroll
  for (int mi = 0; mi < 2; ++mi)
#pragma unroll
    for (int ks = 0; ks < 2; ++ks)
      bq[mi][ks] = ld8(&Qg[(size_t)(mi * 16 + lanem) * HD_ + ks * 32 + quad * 8]);

  f32x4 acc_o[2][4];   // O^T[hd-tile ni][q], C layout
  float lsum[2][4];    // 4 independent partial sums per mi (dep-chain break)
#pragma unroll
  for (int mi = 0; mi < 2; ++mi) {
#pragma unroll
    for (int c = 0; c < 4; ++c) lsum[mi][c] = 0.f;
#pragma unroll
    for (int ni = 0; ni < 4; ++ni) acc_o[mi][ni] = (f32x4){0.f, 0.f, 0.f, 0.f};
  }

  int nIter = qt * 2 + 2;
  int myTiles = (qrow0 >> 6) + 1;

#define STAGE_KV(bufi, s0c)                                                 \
  do {                                                                      \
    gl_lds16(gK + (size_t)(s0c) * HD_,      &Ks[bufi][0][0][0] + wv * 512); \
    gl_lds16(gK + (size_t)(s0c) * HD_ + 32, &Ks[bufi][1][0][0] + wv * 512); \
    gl_lds16(gV + (s0c),                    &Vs[bufi][0][0][0] + wv * 512); \
    gl_lds16(gV + (s0c) + 32,               &Vs[bufi][1][0][0] + wv * 512); \
  } while (0)

  STAGE_KV(0, 0);
  for (int it = 0; it < nIter; ++it) {
    // hardened barrier: drain ALL outstanding memory ops (incl. the in-flight
    // global_load_lds prefetch) before the workgroup barrier.
    __builtin_amdgcn_s_waitcnt(0);
    __syncthreads();
    if (it + 1 < nIter) STAGE_KV((it + 1) & 1, (it + 1) * 64);
    if (it >= myTiles) continue;
    int s0 = it * 64, buf = it & 1;

    // S^T = K * Q^T : accs[mi][ni][i] = S[q=lanem][key = sl(ni,quad,i)]
    f32x4 accs[2][4];
#pragma unroll
    for (int mi = 0; mi < 2; ++mi)
#pragma unroll
      for (int ni = 0; ni < 4; ++ni) accs[mi][ni] = (f32x4){0.f, 0.f, 0.f, 0.f};
#pragma unroll
    for (int ks = 0; ks < 2; ++ks)
#pragma unroll
      for (int ni = 0; ni < 4; ++ni) {
        bf16x8 kf = ld8(&Ks[buf][ks][ni * 16 + lanem][quad * 8]);
        accs[0][ni] = __builtin_amdgcn_mfma_f32_16x16x32_bf16(kf, bq[0][ks], accs[0][ni], 0, 0, 0);
        accs[1][ni] = __builtin_amdgcn_mfma_f32_16x16x32_bf16(kf, bq[1][ks], accs[1][ni], 0, 0, 0);
      }

    // softmax (no-max, exp2; scale folded into Q): local key of accs[.][ni][i]
    // is sl = (ni>>1)*32 + quad*8 + (ni&1)*4 + i  (the staged permutation).
    // lsum partials indexed by i: four independent accumulation chains.
    if (s0 + 63 > qrow0) {
#pragma unroll
      for (int mi = 0; mi < 2; ++mi) {
        int qg = qrow0 + mi * 16 + lanem;
#pragma unroll
        for (int ni = 0; ni < 4; ++ni)
#pragma unroll
          for (int i = 0; i < 4; ++i) {
            int sl = (ni >> 1) * 32 + quad * 8 + (ni & 1) * 4 + i;
            float p = (s0 + sl > qg) ? 0.f : __builtin_amdgcn_exp2f(accs[mi][ni][i]);
            accs[mi][ni][i] = p;
            lsum[mi][i] += p;
          }
      }
    } else {
#pragma unroll
      for (int mi = 0; mi < 2; ++mi)
#pragma unroll
        for (int ni = 0; ni < 4; ++ni)
#pragma unroll
          for (int i = 0; i < 4; ++i) {
            float p = __builtin_amdgcn_exp2f(accs[mi][ni][i]);
            accs[mi][ni][i] = p;
            lsum[mi][i] += p;
          }
    }

    // pack: accs tiles (2c, 2c+1) -> PV B-frag for s-chunk c, directly in regs
#pragma unroll
    for (int c = 0; c < 2; ++c) {
      u32x4 pk0, pk1;
      pk0[0] = pkbf(accs[0][c * 2][0], accs[0][c * 2][1]);
      pk0[1] = pkbf(accs[0][c * 2][2], accs[0][c * 2][3]);
      pk0[2] = pkbf(accs[0][c * 2 + 1][0], accs[0][c * 2 + 1][1]);
      pk0[3] = pkbf(accs[0][c * 2 + 1][2], accs[0][c * 2 + 1][3]);
      pk1[0] = pkbf(accs[1][c * 2][0], accs[1][c * 2][1]);
      pk1[1] = pkbf(accs[1][c * 2][2], accs[1][c * 2][3]);
      pk1[2] = pkbf(accs[1][c * 2 + 1][0], accs[1][c * 2 + 1][1]);
      pk1[3] = pkbf(accs[1][c * 2 + 1][2], accs[1][c * 2 + 1][3]);
      bf16x8 bp0 = __builtin_bit_cast(bf16x8, pk0);
      bf16x8 bp1 = __builtin_bit_cast(bf16x8, pk1);
#pragma unroll
      for (int ni = 0; ni < 4; ++ni) {
        bf16x8 vf = ld8(&Vs[buf][c][ni * 16 + lanem][quad * 8]);
        acc_o[0][ni] = __builtin_amdgcn_mfma_f32_16x16x32_bf16(vf, bp0, acc_o[0][ni], 0, 0, 0);
        acc_o[1][ni] = __builtin_amdgcn_mfma_f32_16x16x32_bf16(vf, bp1, acc_o[1][ni], 0, 0, 0);
      }
    }
  }
#undef STAGE_KV

  // epilogue: O^T[hd=ni*16+quad*4+i][q=qrow0+mi*16+lanem] -> ob[q][h*64+hd]
#pragma unroll
  for (int mi = 0; mi < 2; ++mi) {
    float v = (lsum[mi][0] + lsum[mi][1]) + (lsum[mi][2] + lsum[mi][3]);
    v += __shfl_xor(v, 16);
    v += __shfl_xor(v, 32);
    float inv = 1.f / v;
    int q = qrow0 + mi * 16 + lanem;
    u16* og = ob + ((size_t)b * T_ + q) * D_ + h * HD_;
#pragma unroll
    for (int ni = 0; ni < 4; ++ni) {
      ushort4 st;
      st.x = f2bf(acc_o[mi][ni][0] * inv);
      st.y = f2bf(acc_o[mi][ni][1] * inv);
      st.z = f2bf(acc_o[mi][ni][2] * inv);
      st.w = f2bf(acc_o[mi][ni][3] * inv);
      *(ushort4*)(og + ni * 16 + quad * 4) = st;
    }
  }
}

extern "C" void kernel_launch(void* const* d_in, const int* in_sizes, int n_in,
                              void* d_out, int out_size, void* d_ws, size_t ws_size,
                              hipStream_t stream) {
  const float* x  = (const float*)d_in[0];
  const float* wq = (const float*)d_in[1];
  const float* bq = (const float*)d_in[2];
  const float* wk = (const float*)d_in[3];
  const float* bk = (const float*)d_in[4];
  const float* wv = (const float*)d_in[5];
  const float* bv = (const float*)d_in[6];
  const float* wo = (const float*)d_in[7];
  const float* bo = (const float*)d_in[8];

  char* ws = (char*)d_ws;
  const size_t MB = 1ull << 20;
  u16* xb   = (u16*)(ws + 0 * MB);   // [8192,1024] bf16
  u16* wqkv = (u16*)(ws + 16 * MB);  // [3072,1024] bf16 (wq|wk|wv contiguous)
  u16* wob  = (u16*)(ws + 22 * MB);
  u16* qb   = (u16*)(ws + 24 * MB);  // [B,H,T,HD] bf16 (pre-scaled QSCALE)
  u16* kb   = (u16*)(ws + 40 * MB);  // [B,H,T,HD]
  u16* vtb  = (u16*)(ws + 56 * MB);  // [B,H,HD,T]
  u16* ob   = (u16*)(ws + 72 * MB);  // [8192,1024] bf16

  cvt_all<<<(M_ * D_ + 4 * D_ * D_) / 1024, 256, 0, stream>>>(
      x, wq, wk, wv, wo, xb, wqkv, wqkv + (size_t)D_ * D_, wqkv + 2 * (size_t)D_ * D_, wob);

  gemm_qkv<<<768, 512, 0, stream>>>(xb, wqkv, bq, bk, bv, qb, kb, vtb);

  flash4<<<dim3(T_ / 128, H_, B_), 256, 0, stream>>>(qb, kb, vtb, ob);

  gemm_wo<<<dim3(D_ / 128, M_ / 128), 256, 0, stream>>>(ob, wob, bo, (float*)d_out);
}

// Round 3
// 266.215 us; speedup vs baseline: 1.0125x; 1.0125x over previous
//
#include <hip/hip_runtime.h>
#include <cstdint>

typedef __bf16 bf16x8 __attribute__((ext_vector_type(8)));
typedef float f32x4 __attribute__((ext_vector_type(4)));
typedef uint32_t u32x4 __attribute__((ext_vector_type(4)));
typedef unsigned short u16;

#define B_ 4
#define T_ 2048
#define D_ 1024
#define H_ 16
#define HD_ 64
#define M_ (B_*T_)
// attention scale 1/8 with log2(e) folded in, applied in Q epilogue -> softmax uses exp2
#define QSCALE 0.1803368801111204f

__device__ __forceinline__ u16 f2bf(float f) {
  union { float f; uint32_t u; } x; x.f = f;
  uint32_t u = x.u;
  uint32_t r = (u + 0x7FFFu + ((u >> 16) & 1u)) >> 16;
  return (u16)r;
}

// fast pack: 2 fp32 -> packed bf16x2 via v_perm_b32 (2 adds + 1 perm); p>=0 here.
__device__ __forceinline__ uint32_t pkbf(float a, float b) {
  union { float f; uint32_t u; } x, y; x.f = a; y.f = b;
  uint32_t t0 = x.u + 0x8000u, t1 = y.u + 0x8000u;
  return __builtin_amdgcn_perm(t1, t0, 0x07060302u);  // [t0.b2,t0.b3,t1.b2,t1.b3]
}

__device__ __forceinline__ bf16x8 ld8(const u16* p) {
  return *(const bf16x8*)p;
}

// async global->LDS, 16B per lane; lds ptr must be wave-uniform base (HW adds lane*16)
__device__ __forceinline__ void gl_lds16(const u16* g, u16* l) {
  __builtin_amdgcn_global_load_lds(
      (__attribute__((address_space(1))) void*)(g),
      (__attribute__((address_space(3))) void*)(l), 16, 0, 0);
}

// Fused fp32->bf16 convert of x + 4 weight matrices.
__global__ void cvt_all(const float* __restrict__ x, const float* __restrict__ wq,
                        const float* __restrict__ wk, const float* __restrict__ wv,
                        const float* __restrict__ wo,
                        u16* __restrict__ xb, u16* __restrict__ wqb, u16* __restrict__ wkb,
                        u16* __restrict__ wvb, u16* __restrict__ wob) {
  const long NX = (long)M_ * D_;
  long i = ((long)blockIdx.x * 256 + threadIdx.x) * 4;
  const float* s; u16* d; long j;
  if (i < NX) { s = x; d = xb; j = i; }
  else {
    long r = i - NX; int seg = (int)(r >> 20); j = r & ((1 << 20) - 1);
    s = seg == 0 ? wq : seg == 1 ? wk : seg == 2 ? wv : wo;
    d = seg == 0 ? wqb : seg == 1 ? wkb : seg == 2 ? wvb : wob;
  }
  float4 v = *(const float4*)(s + j);
  ushort4 o;
  o.x = f2bf(v.x); o.y = f2bf(v.y); o.z = f2bf(v.z); o.w = f2bf(v.w);
  *(ushort4*)(d + j) = o;
}

// ---------------------------------------------------------------------------
// gemm_qkv v4: 256x128 tile, 768 blocks (3 uniform rounds), PIPELINED phases.
//   Round-2 post-mortem: MfmaUtil stuck at 30% because each phase drained its
//   ds_reads (lgkmcnt(0)) before MFMA -> LDS serve (1536 cyc/CU/tile) and MFMA
//   (1242 cyc/SIMD/tile) strictly serialized. v4 issues each phase's fragment
//   ds_reads ONE WINDOW EARLY into a double-buffered register set and waits a
//   COUNTED lgkmcnt (4 or 12, never 0 in-loop), so LDS serves under MFMA.
//   Window layout per K-tile kt (2 MFMA phases, mi-halves):
//     W0: issue ldA half1(kt)->afB [4 rd] | stage 3 units(kt+2)->p2
//         barrier; lgkm(4)  [afA+bf(kt) confirmed]; MFMA ph0(afA, bf[kt&1])
//         vmcnt(3) [tile kt+1 landed]; barrier
//     W1: issue ldA half0(kt+1)->afA + ldB(kt+1)->bf[(kt+1)&1] [12 rd]
//         | stage 3 units(kt+2)->p2
//         barrier; lgkm(12) [afB confirmed]; MFMA ph1(afB, bf[kt&1]); barrier
//   WAR ledger: stage(kt+2) targets p2 = tile kt-1 buffer; its last reads
//   (afB of kt-1) are confirmed by W1(kt-1)'s lgkm(12) before the barrier that
//   precedes any W0(kt) stage. vmcnt ledger: 9 outstanding at W0-end (6 of
//   kt+1 + 3 of kt+2) -> vmcnt(3) pins tile kt+1; kt==14 -> vmcnt(0).
//   T2 swizzle + XCD-chunked grid swizzle retained from v3 (proven).
// ---------------------------------------------------------------------------

template <int PH>
__device__ __forceinline__ void ldA_ph(bf16x8 (&af)[2][2], const u16* buf,
                                       int wr, int lanem, int quad) {
#pragma unroll
  for (int mi = 0; mi < 2; ++mi)
#pragma unroll
    for (int ks = 0; ks < 2; ++ks) {
      int row = wr * 64 + (PH * 2 + mi) * 16 + lanem;
      int off = row * 64 + ((ks * 32 + quad * 8) ^ ((lanem & 7) << 3));  // u16 units
      af[mi][ks] = ld8(buf + off);
    }
}

__device__ __forceinline__ void ldB_all(bf16x8 (&bfr)[4][2], const u16* buf,
                                        int wc, int lanem, int quad) {
#pragma unroll
  for (int nj = 0; nj < 4; ++nj)
#pragma unroll
    for (int ks = 0; ks < 2; ++ks) {
      int row = 256 + wc * 64 + nj * 16 + lanem;
      int off = row * 64 + ((ks * 32 + quad * 8) ^ ((lanem & 7) << 3));
      bfr[nj][ks] = ld8(buf + off);
    }
}

template <int PH>
__device__ __forceinline__ void mfmaPH(f32x4 (&acc)[4][4], const bf16x8 (&af)[2][2],
                                       const bf16x8 (&bfr)[4][2]) {
#pragma unroll
  for (int mi = 0; mi < 2; ++mi)
#pragma unroll
    for (int nj = 0; nj < 4; ++nj)
#pragma unroll
      for (int ks = 0; ks < 2; ++ks)
        acc[PH * 2 + mi][nj] = __builtin_amdgcn_mfma_f32_16x16x32_bf16(
            af[mi][ks], bfr[nj][ks], acc[PH * 2 + mi][nj], 0, 0, 0);
}

#define SBAR()                                          \
  __builtin_amdgcn_sched_barrier(0);                    \
  __builtin_amdgcn_s_barrier();                         \
  __builtin_amdgcn_sched_barrier(0)

__global__ __launch_bounds__(512, 2)
void gemm_qkv(const u16* __restrict__ A, const u16* __restrict__ Bw,
              const float* __restrict__ bq, const float* __restrict__ bk,
              const float* __restrict__ bv,
              u16* __restrict__ qb, u16* __restrict__ kb, u16* __restrict__ vtb) {
  __shared__ union {
    u16 S[3][384][64];   // 3 bufs x (A rows 0..255 | B rows 256..383) x 64k = 144 KiB
    u16 C[256 * 136];    // epilogue bounce: Q/K [256][136]; V uses [128][264]
  } sm;

  const int tid = threadIdx.x;
  const int wv = tid >> 6, lane = tid & 63;
  const int lanem = lane & 15, quad = lane >> 4;
  const int wr = wv >> 1, wc = wv & 1;   // wave grid 4 (M) x 2 (N)

  // XCD-chunked bijective swizzle: 96 consecutive tiles (= 4 m-rows) per XCD
  const int l = ((int)blockIdx.x & 7) * 96 + ((int)blockIdx.x >> 3);
  const int n0 = (l % 24) * 128, m0 = (l / 24) * 256;

  // per-lane pre-swizzled global source (T2 involution, row&7 == grow)
  const int grow = lane >> 3;
  const int gcol = (((lane & 7) ^ grow) * 8);

  // stage unit u: u<4 -> A rows [u*64,u*64+64); u>=4 -> B rows [(u-4)*64, ...)
  auto stage = [&](u16* bufbase, int u, int k0) {
    const u16* src = (u < 4)
        ? A  + (size_t)(m0 + u * 64 + wv * 8 + grow) * D_ + k0 + gcol
        : Bw + (size_t)(n0 + (u - 4) * 64 + wv * 8 + grow) * D_ + k0 + gcol;
    gl_lds16(src, bufbase + (u * 64 + wv * 8) * 64);
  };

  f32x4 acc[4][4];
#pragma unroll
  for (int a = 0; a < 4; ++a)
#pragma unroll
    for (int b = 0; b < 4; ++b) acc[a][b] = (f32x4){0.f, 0.f, 0.f, 0.f};

  bf16x8 afA[2][2], afB[2][2];   // A-half frags: afA = half0(cur tile), afB = half1
  bf16x8 bf2[2][4][2];           // B frags, double-buffered by tile parity

  u16* p0 = &sm.S[0][0][0];   // tile kt (read)
  u16* p1 = &sm.S[1][0][0];   // tile kt+1 (landing/read-ahead)
  u16* p2 = &sm.S[2][0][0];   // tile kt+2 (stage target)

  // prologue: tile0 -> buf0, tile1 -> buf1; wait tile0 landed (6 remain).
#pragma unroll
  for (int u = 0; u < 6; ++u) stage(p0, u, 0);
#pragma unroll
  for (int u = 0; u < 6; ++u) stage(p1, u, 64);
  asm volatile("s_waitcnt vmcnt(6)" ::: "memory");
  __builtin_amdgcn_s_barrier();
  __builtin_amdgcn_sched_barrier(0);
  // preload frags for phase(0,0): 12 ds_reads in flight
  ldA_ph<0>(afA, p0, wr, lanem, quad);
  ldB_all(bf2[0], p0, wc, lanem, quad);

#pragma unroll 2
  for (int kt = 0; kt < 16; ++kt) {
    const int k2 = (kt + 2) << 6;

    // ---- W0: issue ph1 frags + 3 stages, then MFMA ph0 (frags from last W1)
    ldA_ph<1>(afB, p0, wr, lanem, quad);                         // +4 rd
    if (kt < 14) { stage(p2, 0, k2); stage(p2, 1, k2); stage(p2, 2, k2); }
    SBAR();
    asm volatile("s_waitcnt lgkmcnt(4)" ::: "memory");           // afA+bf(kt) done
    __builtin_amdgcn_sched_barrier(0);
    __builtin_amdgcn_s_setprio(1);
    mfmaPH<0>(acc, afA, bf2[kt & 1]);
    __builtin_amdgcn_s_setprio(0);
    if (kt < 14)       asm volatile("s_waitcnt vmcnt(3)" ::: "memory");  // kt+1 landed
    else if (kt == 14) asm volatile("s_waitcnt vmcnt(0)" ::: "memory");
    SBAR();

    // ---- W1: issue next tile's ph0 frags + 3 stages, then MFMA ph1
    if (kt < 15) {
      ldA_ph<0>(afA, p1, wr, lanem, quad);                       // +4 rd
      ldB_all(bf2[(kt + 1) & 1], p1, wc, lanem, quad);           // +8 rd
    }
    if (kt < 14) { stage(p2, 3, k2); stage(p2, 4, k2); stage(p2, 5, k2); }
    SBAR();
    if (kt < 15) asm volatile("s_waitcnt lgkmcnt(12)" ::: "memory");  // afB done
    else         asm volatile("s_waitcnt lgkmcnt(0)" ::: "memory");
    __builtin_amdgcn_sched_barrier(0);
    __builtin_amdgcn_s_setprio(1);
    mfmaPH<1>(acc, afB, bf2[kt & 1]);
    __builtin_amdgcn_s_setprio(0);
    SBAR();

    u16* t = p0; p0 = p1; p1 = p2; p2 = t;
  }

  // ---- epilogue: bounce through the (now free) LDS union
  const int seg = n0 >> 10, n0l = n0 & 1023;   // BN=128 divides 1024: no crossing
  const int bb = m0 >> 11, tl0 = m0 & (T_ - 1);

  if (seg == 2) {
    // V: transposed bounce [128 ncol][264 (256 t + pad)], single pass
    __syncthreads();
#pragma unroll
    for (int a = 0; a < 4; ++a)
#pragma unroll
      for (int nj = 0; nj < 4; ++nj) {
        int ncol = wc * 64 + nj * 16 + lanem;
        float bvv = bv[n0l + ncol];
        int mb = wr * 64 + a * 16 + quad * 4;
        ushort4 w4;
        w4.x = f2bf(acc[a][nj][0] + bvv);
        w4.y = f2bf(acc[a][nj][1] + bvv);
        w4.z = f2bf(acc[a][nj][2] + bvv);
        w4.w = f2bf(acc[a][nj][3] + bvv);
        *(ushort4*)&sm.C[ncol * 264 + mb] = w4;
      }
    __syncthreads();
#pragma unroll
    for (int it = 0; it < 8; ++it) {
      int chunk = it * 512 + tid;
      int nrow = chunk >> 5, c8 = chunk & 31;
      int gnl = n0l + nrow;
      int hh = gnl >> 6, hd = gnl & 63;
      *(uint4*)&vtb[(((size_t)bb * H_ + hh) * HD_ + hd) * T_ + tl0 + c8 * 8] =
          *(const uint4*)&sm.C[nrow * 264 + c8 * 8];
    }
  } else {
    // Q/K: [256 t][136 (128 hd-cols + pad)] bounce, single pass
    const float* bias = seg == 0 ? bq : bk;
    u16* out = seg == 0 ? qb : kb;
    const float sc = seg == 0 ? QSCALE : 1.0f;
    __syncthreads();
#pragma unroll
    for (int a = 0; a < 4; ++a)
#pragma unroll
      for (int nj = 0; nj < 4; ++nj) {
        int col = wc * 64 + nj * 16 + lanem;
        float bvv = bias[n0l + col];
        int r = wr * 64 + a * 16 + quad * 4;
#pragma unroll
        for (int i = 0; i < 4; ++i)
          sm.C[(r + i) * 136 + col] = f2bf((acc[a][nj][i] + bvv) * sc);
      }
    __syncthreads();
#pragma unroll
    for (int it = 0; it < 8; ++it) {
      int chunk = it * 512 + tid;
      int row = chunk >> 4, c8 = chunk & 15;
      int col0 = c8 * 8;
      int hh = (n0l + col0) >> 6, hd = col0 & 63;
      int t = tl0 + row;
      *(uint4*)&out[(((size_t)bb * H_ + hh) * T_ + t) * HD_ + hd] =
          *(const uint4*)&sm.C[row * 136 + col0];
    }
  }
}

// Output projection: C = ob(8192x1024) * wo(1024x1024)^T + bo, fp32 out.
// 128x128 tile, BK=64, (256,3). Grid 8x64 = 512 blocks -> 2/CU, uniform.
__global__ __launch_bounds__(256, 3)
void gemm_wo(const u16* __restrict__ A, const u16* __restrict__ Bw,
             const float* __restrict__ bias, float* __restrict__ Co) {
  __shared__ u16 S[2][2][4096];   // [matrix][panel ks][128*32]
  int tid = threadIdx.x;
  int n0 = blockIdx.x * 128, m0 = blockIdx.y * 128;
  int wv = tid >> 6, lane = tid & 63, lanem = lane & 15, quad = lane >> 4;
  int wm = (wv >> 1) * 64, wn = (wv & 1) * 64;

  int rA = wv * 16 + (lane >> 2);
  int cc = (lane & 3) * 8;
  const u16* Ab = A + (size_t)(m0 + rA) * D_ + cc;
  const u16* Bb = Bw + (size_t)(n0 + rA) * D_ + cc;

  f32x4 acc[4][4];
#pragma unroll
  for (int mi = 0; mi < 4; ++mi)
#pragma unroll
    for (int ni = 0; ni < 4; ++ni)
      acc[mi][ni] = (f32x4){0.f, 0.f, 0.f, 0.f};

  for (int kt = 0; kt < 16; ++kt) {
    int k0 = kt * 64;
    __syncthreads();
#pragma unroll
    for (int ks = 0; ks < 2; ++ks)
#pragma unroll
      for (int j = 0; j < 2; ++j) {
        gl_lds16(Ab + k0 + ks * 32 + (size_t)j * 64 * D_,
                 &S[0][ks][(j * 256 + wv * 64) * 8]);
        gl_lds16(Bb + k0 + ks * 32 + (size_t)j * 64 * D_,
                 &S[1][ks][(j * 256 + wv * 64) * 8]);
      }
    __syncthreads();
#pragma unroll
    for (int ks = 0; ks < 2; ++ks) {
      bf16x8 af[4], bfr[4];
#pragma unroll
      for (int mi = 0; mi < 4; ++mi)
        af[mi] = ld8(&S[0][ks][(wm + mi * 16 + lanem) * 32 + quad * 8]);
#pragma unroll
      for (int ni = 0; ni < 4; ++ni)
        bfr[ni] = ld8(&S[1][ks][(wn + ni * 16 + lanem) * 32 + quad * 8]);
#pragma unroll
      for (int mi = 0; mi < 4; ++mi)
#pragma unroll
        for (int ni = 0; ni < 4; ++ni)
          acc[mi][ni] = __builtin_amdgcn_mfma_f32_16x16x32_bf16(af[mi], bfr[ni], acc[mi][ni], 0, 0, 0);
    }
  }

#pragma unroll
  for (int ni = 0; ni < 4; ++ni) {
    int gn = n0 + wn + ni * 16 + lanem;
    float bvv = bias[gn];
#pragma unroll
    for (int mi = 0; mi < 4; ++mi)
#pragma unroll
      for (int i = 0; i < 4; ++i) {
        int gm = m0 + wm + mi * 16 + quad * 4 + i;
        Co[(size_t)gm * D_ + gn] = acc[mi][ni][i] + bvv;
      }
  }
}

// Flash attention v5: round-2 core + conflict-free K/V LDS ([64][64] rows =
// 32-bank stride + XOR-chunk swizzle, same involution as the gemm staging).
// Round-2 PMC: SQ_LDS_BANK_CONFLICT 4.3M (8-way on the old 64B-stride rows).
// Staging: 8 lanes/row, per-lane global source chunk = (lane&7)^(lane>>3);
// key permutation (and thus the sl formula + causal mask) unchanged.
__global__ __launch_bounds__(256, 4)
void flash4(const u16* __restrict__ qb, const u16* __restrict__ kb,
            const u16* __restrict__ vtb, u16* __restrict__ ob) {
  __shared__ u16 Ks[2][64][64];   // [buf][slot(permuted key)][d], XOR-swizzled
  __shared__ u16 Vs[2][64][64];   // [buf][hd][s], XOR-swizzled
  int tid = threadIdx.x, wv = tid >> 6, lane = tid & 63;
  int lanem = lane & 15, quad = lane >> 4;
  int h = blockIdx.y, b = blockIdx.z;
  int z = (int)blockIdx.z;
  int qt = ((int)blockIdx.x ^ ((z & 1) * 15) ^ ((z >> 1) * 3)) & 15;
  size_t bh = (size_t)b * H_ + h;
  int qrow0 = qt * 128 + wv * 32;
  const u16* Qg = qb + (bh * T_ + qrow0) * HD_;
  const u16* Kg = kb + bh * T_ * HD_;
  const u16* Vg = vtb + bh * HD_ * T_;

  // staging geometry: 8 lanes per 128B row; r8 = row-within-unit, swizzled col
  int r8 = lane >> 3, c8 = lane & 7;
  int scol = ((c8 ^ r8) * 8);
  int slot0 = wv * 8 + r8, slot1 = 32 + wv * 8 + r8;
  // permuted key rows for K (permutation preserved from v4r2)
  auto keyf = [](int s) {
    return (s >> 5) * 32 + (((s & 15) >> 2) * 8) + (((s >> 4) & 1) * 4) + (s & 3);
  };
  const u16* gK0 = Kg + (size_t)keyf(slot0) * HD_ + scol;
  const u16* gK1 = Kg + (size_t)keyf(slot1) * HD_ + scol;
  const u16* gV0 = Vg + (size_t)slot0 * T_ + scol;
  const u16* gV1 = Vg + (size_t)slot1 * T_ + scol;

  // Q as B-operand fragments (B[n=q=lanem][k=d=quad*8+j])
  bf16x8 bq[2][2];
#pragma unroll
  for (int mi = 0; mi < 2; ++mi)
#pragma unroll
    for (int ks = 0; ks < 2; ++ks)
      bq[mi][ks] = ld8(&Qg[(size_t)(mi * 16 + lanem) * HD_ + ks * 32 + quad * 8]);

  f32x4 acc_o[2][4];   // O^T[hd-tile ni][q], C layout
  float lsum[2][4];    // 4 independent partial sums per mi (dep-chain break)
#pragma unroll
  for (int mi = 0; mi < 2; ++mi) {
#pragma unroll
    for (int c = 0; c < 4; ++c) lsum[mi][c] = 0.f;
#pragma unroll
    for (int ni = 0; ni < 4; ++ni) acc_o[mi][ni] = (f32x4){0.f, 0.f, 0.f, 0.f};
  }

  int nIter = qt * 2 + 2;
  int myTiles = (qrow0 >> 6) + 1;

#define STAGE_KV(bufi, s0c)                                              \
  do {                                                                   \
    gl_lds16(gK0 + (size_t)(s0c) * HD_, &Ks[bufi][0][0] + slot0 * 64 - r8 * 64); \
    gl_lds16(gK1 + (size_t)(s0c) * HD_, &Ks[bufi][0][0] + slot1 * 64 - r8 * 64); \
    gl_lds16(gV0 + (s0c),               &Vs[bufi][0][0] + slot0 * 64 - r8 * 64); \
    gl_lds16(gV1 + (s0c),               &Vs[bufi][0][0] + slot1 * 64 - r8 * 64); \
  } while (0)
  // note: LDS dest must be the wave-uniform base (HW adds lane*16B). slotX*64 -
  // r8*64 == (unit base row)*64, uniform across the wave's lanes.

  STAGE_KV(0, 0);
  for (int it = 0; it < nIter; ++it) {
    // hardened barrier: drain ALL outstanding memory ops (incl. the in-flight
    // global_load_lds prefetch) before the workgroup barrier.
    __builtin_amdgcn_s_waitcnt(0);
    __syncthreads();
    if (it + 1 < nIter) STAGE_KV((it + 1) & 1, (it + 1) * 64);
    if (it >= myTiles) continue;
    int s0 = it * 64, buf = it & 1;
    const u16* Kb = &Ks[buf][0][0];
    const u16* Vb = &Vs[buf][0][0];

    // S^T = K * Q^T : accs[mi][ni][i] = S[q=lanem][key = sl(ni,quad,i)]
    f32x4 accs[2][4];
#pragma unroll
    for (int mi = 0; mi < 2; ++mi)
#pragma unroll
      for (int ni = 0; ni < 4; ++ni) accs[mi][ni] = (f32x4){0.f, 0.f, 0.f, 0.f};
#pragma unroll
    for (int ks = 0; ks < 2; ++ks)
#pragma unroll
      for (int ni = 0; ni < 4; ++ni) {
        int row = ni * 16 + lanem;
        bf16x8 kf = ld8(Kb + row * 64 + (((ks * 4 + quad) ^ (lanem & 7)) * 8));
        accs[0][ni] = __builtin_amdgcn_mfma_f32_16x16x32_bf16(kf, bq[0][ks], accs[0][ni], 0, 0, 0);
        accs[1][ni] = __builtin_amdgcn_mfma_f32_16x16x32_bf16(kf, bq[1][ks], accs[1][ni], 0, 0, 0);
      }

    // softmax (no-max, exp2; scale folded into Q): local key of accs[.][ni][i]
    // is sl = (ni>>1)*32 + quad*8 + (ni&1)*4 + i  (the staged permutation).
    // lsum partials indexed by i: four independent accumulation chains.
    if (s0 + 63 > qrow0) {
#pragma unroll
      for (int mi = 0; mi < 2; ++mi) {
        int qg = qrow0 + mi * 16 + lanem;
#pragma unroll
        for (int ni = 0; ni < 4; ++ni)
#pragma unroll
          for (int i = 0; i < 4; ++i) {
            int sl = (ni >> 1) * 32 + quad * 8 + (ni & 1) * 4 + i;
            float p = (s0 + sl > qg) ? 0.f : __builtin_amdgcn_exp2f(accs[mi][ni][i]);
            accs[mi][ni][i] = p;
            lsum[mi][i] += p;
          }
      }
    } else {
#pragma unroll
      for (int mi = 0; mi < 2; ++mi)
#pragma unroll
        for (int ni = 0; ni < 4; ++ni)
#pragma unroll
          for (int i = 0; i < 4; ++i) {
            float p = __builtin_amdgcn_exp2f(accs[mi][ni][i]);
            accs[mi][ni][i] = p;
            lsum[mi][i] += p;
          }
    }

    // pack: accs tiles (2c, 2c+1) -> PV B-frag for s-chunk c, directly in regs
#pragma unroll
    for (int c = 0; c < 2; ++c) {
      u32x4 pk0, pk1;
      pk0[0] = pkbf(accs[0][c * 2][0], accs[0][c * 2][1]);
      pk0[1] = pkbf(accs[0][c * 2][2], accs[0][c * 2][3]);
      pk0[2] = pkbf(accs[0][c * 2 + 1][0], accs[0][c * 2 + 1][1]);
      pk0[3] = pkbf(accs[0][c * 2 + 1][2], accs[0][c * 2 + 1][3]);
      pk1[0] = pkbf(accs[1][c * 2][0], accs[1][c * 2][1]);
      pk1[1] = pkbf(accs[1][c * 2][2], accs[1][c * 2][3]);
      pk1[2] = pkbf(accs[1][c * 2 + 1][0], accs[1][c * 2 + 1][1]);
      pk1[3] = pkbf(accs[1][c * 2 + 1][2], accs[1][c * 2 + 1][3]);
      bf16x8 bp0 = __builtin_bit_cast(bf16x8, pk0);
      bf16x8 bp1 = __builtin_bit_cast(bf16x8, pk1);
#pragma unroll
      for (int ni = 0; ni < 4; ++ni) {
        int row = ni * 16 + lanem;
        bf16x8 vf = ld8(Vb + row * 64 + (((c * 4 + quad) ^ (lanem & 7)) * 8));
        acc_o[0][ni] = __builtin_amdgcn_mfma_f32_16x16x32_bf16(vf, bp0, acc_o[0][ni], 0, 0, 0);
        acc_o[1][ni] = __builtin_amdgcn_mfma_f32_16x16x32_bf16(vf, bp1, acc_o[1][ni], 0, 0, 0);
      }
    }
  }
#undef STAGE_KV

  // epilogue: O^T[hd=ni*16+quad*4+i][q=qrow0+mi*16+lanem] -> ob[q][h*64+hd]
#pragma unroll
  for (int mi = 0; mi < 2; ++mi) {
    float v = (lsum[mi][0] + lsum[mi][1]) + (lsum[mi][2] + lsum[mi][3]);
    v += __shfl_xor(v, 16);
    v += __shfl_xor(v, 32);
    float inv = 1.f / v;
    int q = qrow0 + mi * 16 + lanem;
    u16* og = ob + ((size_t)b * T_ + q) * D_ + h * HD_;
#pragma unroll
    for (int ni = 0; ni < 4; ++ni) {
      ushort4 st;
      st.x = f2bf(acc_o[mi][ni][0] * inv);
      st.y = f2bf(acc_o[mi][ni][1] * inv);
      st.z = f2bf(acc_o[mi][ni][2] * inv);
      st.w = f2bf(acc_o[mi][ni][3] * inv);
      *(ushort4*)(og + ni * 16 + quad * 4) = st;
    }
  }
}

extern "C" void kernel_launch(void* const* d_in, const int* in_sizes, int n_in,
                              void* d_out, int out_size, void* d_ws, size_t ws_size,
                              hipStream_t stream) {
  const float* x  = (const float*)d_in[0];
  const float* wq = (const float*)d_in[1];
  const float* bq = (const float*)d_in[2];
  const float* wk = (const float*)d_in[3];
  const float* bk = (const float*)d_in[4];
  const float* wv = (const float*)d_in[5];
  const float* bv = (const float*)d_in[6];
  const float* wo = (const float*)d_in[7];
  const float* bo = (const float*)d_in[8];

  char* ws = (char*)d_ws;
  const size_t MB = 1ull << 20;
  u16* xb   = (u16*)(ws + 0 * MB);   // [8192,1024] bf16
  u16* wqkv = (u16*)(ws + 16 * MB);  // [3072,1024] bf16 (wq|wk|wv contiguous)
  u16* wob  = (u16*)(ws + 22 * MB);
  u16* qb   = (u16*)(ws + 24 * MB);  // [B,H,T,HD] bf16 (pre-scaled QSCALE)
  u16* kb   = (u16*)(ws + 40 * MB);  // [B,H,T,HD]
  u16* vtb  = (u16*)(ws + 56 * MB);  // [B,H,HD,T]
  u16* ob   = (u16*)(ws + 72 * MB);  // [8192,1024] bf16

  cvt_all<<<(M_ * D_ + 4 * D_ * D_) / 1024, 256, 0, stream>>>(
      x, wq, wk, wv, wo, xb, wqkv, wqkv + (size_t)D_ * D_, wqkv + 2 * (size_t)D_ * D_, wob);

  gemm_qkv<<<768, 512, 0, stream>>>(xb, wqkv, bq, bk, bv, qb, kb, vtb);

  flash4<<<dim3(T_ / 128, H_, B_), 256, 0, stream>>>(qb, kb, vtb, ob);

  gemm_wo<<<dim3(D_ / 128, M_ / 128), 256, 0, stream>>>(ob, wob, bo, (float*)d_out);
}

// Round 5
// 262.002 us; speedup vs baseline: 1.0288x; 1.0161x over previous
//
#include <hip/hip_runtime.h>
#include <cstdint>

typedef __bf16 bf16x8 __attribute__((ext_vector_type(8)));
typedef float f32x4 __attribute__((ext_vector_type(4)));
typedef uint32_t u32x4 __attribute__((ext_vector_type(4)));
typedef unsigned short u16;

#define B_ 4
#define T_ 2048
#define D_ 1024
#define H_ 16
#define HD_ 64
#define M_ (B_*T_)
// attention scale 1/8 with log2(e) folded in, applied in Q epilogue -> softmax uses exp2
#define QSCALE 0.1803368801111204f

__device__ __forceinline__ u16 f2bf(float f) {
  union { float f; uint32_t u; } x; x.f = f;
  uint32_t u = x.u;
  uint32_t r = (u + 0x7FFFu + ((u >> 16) & 1u)) >> 16;
  return (u16)r;
}

// fast pack: 2 fp32 -> packed bf16x2 via v_perm_b32 (2 adds + 1 perm); p>=0 here.
__device__ __forceinline__ uint32_t pkbf(float a, float b) {
  union { float f; uint32_t u; } x, y; x.f = a; y.f = b;
  uint32_t t0 = x.u + 0x8000u, t1 = y.u + 0x8000u;
  return __builtin_amdgcn_perm(t1, t0, 0x07060302u);  // [t0.b2,t0.b3,t1.b2,t1.b3]
}

__device__ __forceinline__ bf16x8 ld8(const u16* p) {
  return *(const bf16x8*)p;
}

// async global->LDS, 16B per lane; lds ptr must be wave-uniform base (HW adds lane*16)
__device__ __forceinline__ void gl_lds16(const u16* g, u16* l) {
  __builtin_amdgcn_global_load_lds(
      (__attribute__((address_space(1))) void*)(g),
      (__attribute__((address_space(3))) void*)(l), 16, 0, 0);
}

// Fused fp32->bf16 convert of x + 4 weight matrices.
__global__ void cvt_all(const float* __restrict__ x, const float* __restrict__ wq,
                        const float* __restrict__ wk, const float* __restrict__ wv,
                        const float* __restrict__ wo,
                        u16* __restrict__ xb, u16* __restrict__ wqb, u16* __restrict__ wkb,
                        u16* __restrict__ wvb, u16* __restrict__ wob) {
  const long NX = (long)M_ * D_;
  long i = ((long)blockIdx.x * 256 + threadIdx.x) * 4;
  const float* s; u16* d; long j;
  if (i < NX) { s = x; d = xb; j = i; }
  else {
    long r = i - NX; int seg = (int)(r >> 20); j = r & ((1 << 20) - 1);
    s = seg == 0 ? wq : seg == 1 ? wk : seg == 2 ? wv : wo;
    d = seg == 0 ? wqb : seg == 1 ? wkb : seg == 2 ? wvb : wob;
  }
  float4 v = *(const float4*)(s + j);
  ushort4 o;
  o.x = f2bf(v.x); o.y = f2bf(v.y); o.z = f2bf(v.z); o.w = f2bf(v.w);
  *(ushort4*)(d + j) = o;
}

// ---------------------------------------------------------------------------
// Pipelined 256x128 GEMM skeleton (v4): validated on gemm_qkv in round 3
// (replay-green). Round 4 applied it to gemm_wo and the build FAILED the
// replay tripwire (stochastic race, absmax 0.307 post-timing only).
// ISOLATION THIS ROUND: gemm_wo reverted to the round-0 kernel; the v4
// skeleton remains ONLY in gemm_qkv for a second independent replay trial.
// ---------------------------------------------------------------------------

template <int PH>
__device__ __forceinline__ void ldA_ph(bf16x8 (&af)[2][2], const u16* buf,
                                       int wr, int lanem, int quad) {
#pragma unroll
  for (int mi = 0; mi < 2; ++mi)
#pragma unroll
    for (int ks = 0; ks < 2; ++ks) {
      int row = wr * 64 + (PH * 2 + mi) * 16 + lanem;
      int off = row * 64 + ((ks * 32 + quad * 8) ^ ((lanem & 7) << 3));  // u16 units
      af[mi][ks] = ld8(buf + off);
    }
}

__device__ __forceinline__ void ldB_all(bf16x8 (&bfr)[4][2], const u16* buf,
                                        int wc, int lanem, int quad) {
#pragma unroll
  for (int nj = 0; nj < 4; ++nj)
#pragma unroll
    for (int ks = 0; ks < 2; ++ks) {
      int row = 256 + wc * 64 + nj * 16 + lanem;
      int off = row * 64 + ((ks * 32 + quad * 8) ^ ((lanem & 7) << 3));
      bfr[nj][ks] = ld8(buf + off);
    }
}

template <int PH>
__device__ __forceinline__ void mfmaPH(f32x4 (&acc)[4][4], const bf16x8 (&af)[2][2],
                                       const bf16x8 (&bfr)[4][2]) {
#pragma unroll
  for (int mi = 0; mi < 2; ++mi)
#pragma unroll
    for (int nj = 0; nj < 4; ++nj)
#pragma unroll
      for (int ks = 0; ks < 2; ++ks)
        acc[PH * 2 + mi][nj] = __builtin_amdgcn_mfma_f32_16x16x32_bf16(
            af[mi][ks], bfr[nj][ks], acc[PH * 2 + mi][nj], 0, 0, 0);
}

#define SBAR()                                          \
  __builtin_amdgcn_sched_barrier(0);                    \
  __builtin_amdgcn_s_barrier();                         \
  __builtin_amdgcn_sched_barrier(0)

__global__ __launch_bounds__(512, 2)
void gemm_qkv(const u16* __restrict__ A, const u16* __restrict__ Bw,
              const float* __restrict__ bq, const float* __restrict__ bk,
              const float* __restrict__ bv,
              u16* __restrict__ qb, u16* __restrict__ kb, u16* __restrict__ vtb) {
  __shared__ union {
    u16 S[3][384][64];   // 3 bufs x (A rows 0..255 | B rows 256..383) x 64k = 144 KiB
    u16 C[256 * 136];    // epilogue bounce: Q/K [256][136]; V uses [128][264]
  } sm;

  const int tid = threadIdx.x;
  const int wv = tid >> 6, lane = tid & 63;
  const int lanem = lane & 15, quad = lane >> 4;
  const int wr = wv >> 1, wc = wv & 1;   // wave grid 4 (M) x 2 (N)

  // XCD-chunked bijective swizzle: 96 consecutive tiles (= 4 m-rows) per XCD
  const int l = ((int)blockIdx.x & 7) * 96 + ((int)blockIdx.x >> 3);
  const int n0 = (l % 24) * 128, m0 = (l / 24) * 256;

  // per-lane pre-swizzled global source (T2 involution, row&7 == grow)
  const int grow = lane >> 3;
  const int gcol = (((lane & 7) ^ grow) * 8);

  // stage unit u: u<4 -> A rows [u*64,u*64+64); u>=4 -> B rows [(u-4)*64, ...)
  auto stage = [&](u16* bufbase, int u, int k0) {
    const u16* src = (u < 4)
        ? A  + (size_t)(m0 + u * 64 + wv * 8 + grow) * D_ + k0 + gcol
        : Bw + (size_t)(n0 + (u - 4) * 64 + wv * 8 + grow) * D_ + k0 + gcol;
    gl_lds16(src, bufbase + (u * 64 + wv * 8) * 64);
  };

  f32x4 acc[4][4];
#pragma unroll
  for (int a = 0; a < 4; ++a)
#pragma unroll
    for (int b = 0; b < 4; ++b) acc[a][b] = (f32x4){0.f, 0.f, 0.f, 0.f};

  bf16x8 afA[2][2], afB[2][2];   // A-half frags (window double-buffer)
  bf16x8 bf2[2][4][2];           // B frags, double-buffered by tile parity

  u16* p0 = &sm.S[0][0][0];   // tile kt (read)
  u16* p1 = &sm.S[1][0][0];   // tile kt+1 (landing/read-ahead)
  u16* p2 = &sm.S[2][0][0];   // tile kt+2 (stage target)

  // prologue: tile0 -> buf0, tile1 -> buf1; wait tile0 landed (6 remain).
#pragma unroll
  for (int u = 0; u < 6; ++u) stage(p0, u, 0);
#pragma unroll
  for (int u = 0; u < 6; ++u) stage(p1, u, 64);
  asm volatile("s_waitcnt vmcnt(6)" ::: "memory");
  __builtin_amdgcn_s_barrier();
  __builtin_amdgcn_sched_barrier(0);
  // preload frags for phase(0,0): 12 ds_reads in flight
  ldA_ph<0>(afA, p0, wr, lanem, quad);
  ldB_all(bf2[0], p0, wc, lanem, quad);

#pragma unroll 2
  for (int kt = 0; kt < 16; ++kt) {
    const int k2 = (kt + 2) << 6;

    // ---- W0: issue ph1 frags + 3 stages, then MFMA ph0 (frags from last W1)
    ldA_ph<1>(afB, p0, wr, lanem, quad);                         // +4 rd
    if (kt < 14) { stage(p2, 0, k2); stage(p2, 1, k2); stage(p2, 2, k2); }
    SBAR();
    asm volatile("s_waitcnt lgkmcnt(4)" ::: "memory");           // afA+bf(kt) done
    __builtin_amdgcn_sched_barrier(0);
    __builtin_amdgcn_s_setprio(1);
    mfmaPH<0>(acc, afA, bf2[kt & 1]);
    __builtin_amdgcn_s_setprio(0);
    if (kt < 14)       asm volatile("s_waitcnt vmcnt(3)" ::: "memory");  // kt+1 landed
    else if (kt == 14) asm volatile("s_waitcnt vmcnt(0)" ::: "memory");
    SBAR();

    // ---- W1: issue next tile's ph0 frags + 3 stages, then MFMA ph1
    if (kt < 15) {
      ldA_ph<0>(afA, p1, wr, lanem, quad);                       // +4 rd
      ldB_all(bf2[(kt + 1) & 1], p1, wc, lanem, quad);           // +8 rd
    }
    if (kt < 14) { stage(p2, 3, k2); stage(p2, 4, k2); stage(p2, 5, k2); }
    SBAR();
    if (kt < 15) asm volatile("s_waitcnt lgkmcnt(12)" ::: "memory");  // afB done
    else         asm volatile("s_waitcnt lgkmcnt(0)" ::: "memory");
    __builtin_amdgcn_sched_barrier(0);
    __builtin_amdgcn_s_setprio(1);
    mfmaPH<1>(acc, afB, bf2[kt & 1]);
    __builtin_amdgcn_s_setprio(0);
    SBAR();

    u16* t = p0; p0 = p1; p1 = p2; p2 = t;
  }

  // ---- epilogue: bounce through the (now free) LDS union
  const int seg = n0 >> 10, n0l = n0 & 1023;   // BN=128 divides 1024: no crossing
  const int bb = m0 >> 11, tl0 = m0 & (T_ - 1);

  if (seg == 2) {
    // V: transposed bounce [128 ncol][264 (256 t + pad)], single pass
    __syncthreads();
#pragma unroll
    for (int a = 0; a < 4; ++a)
#pragma unroll
      for (int nj = 0; nj < 4; ++nj) {
        int ncol = wc * 64 + nj * 16 + lanem;
        float bvv = bv[n0l + ncol];
        int mb = wr * 64 + a * 16 + quad * 4;
        ushort4 w4;
        w4.x = f2bf(acc[a][nj][0] + bvv);
        w4.y = f2bf(acc[a][nj][1] + bvv);
        w4.z = f2bf(acc[a][nj][2] + bvv);
        w4.w = f2bf(acc[a][nj][3] + bvv);
        *(ushort4*)&sm.C[ncol * 264 + mb] = w4;
      }
    __syncthreads();
#pragma unroll
    for (int it = 0; it < 8; ++it) {
      int chunk = it * 512 + tid;
      int nrow = chunk >> 5, c8 = chunk & 31;
      int gnl = n0l + nrow;
      int hh = gnl >> 6, hd = gnl & 63;
      *(uint4*)&vtb[(((size_t)bb * H_ + hh) * HD_ + hd) * T_ + tl0 + c8 * 8] =
          *(const uint4*)&sm.C[nrow * 264 + c8 * 8];
    }
  } else {
    // Q/K: [256 t][136 (128 hd-cols + pad)] bounce, single pass
    const float* bias = seg == 0 ? bq : bk;
    u16* out = seg == 0 ? qb : kb;
    const float sc = seg == 0 ? QSCALE : 1.0f;
    __syncthreads();
#pragma unroll
    for (int a = 0; a < 4; ++a)
#pragma unroll
      for (int nj = 0; nj < 4; ++nj) {
        int col = wc * 64 + nj * 16 + lanem;
        float bvv = bias[n0l + col];
        int r = wr * 64 + a * 16 + quad * 4;
#pragma unroll
        for (int i = 0; i < 4; ++i)
          sm.C[(r + i) * 136 + col] = f2bf((acc[a][nj][i] + bvv) * sc);
      }
    __syncthreads();
#pragma unroll
    for (int it = 0; it < 8; ++it) {
      int chunk = it * 512 + tid;
      int row = chunk >> 4, c8 = chunk & 15;
      int col0 = c8 * 8;
      int hh = (n0l + col0) >> 6, hd = col0 & 63;
      int t = tl0 + row;
      *(uint4*)&out[(((size_t)bb * H_ + hh) * T_ + t) * HD_ + hd] =
          *(const uint4*)&sm.C[row * 136 + col0];
    }
  }
}

// Output projection: REVERTED to round-0 kernel (replay-green rounds 0-3).
// C = ob(8192x1024) * wo(1024x1024)^T + bo, fp32 out.
// 128x128 tile, BK=64, (256,3). Grid 8x64 = 512 blocks.
__global__ __launch_bounds__(256, 3)
void gemm_wo(const u16* __restrict__ A, const u16* __restrict__ Bw,
             const float* __restrict__ bias, float* __restrict__ Co) {
  __shared__ u16 S[2][2][4096];   // [matrix][panel ks][128*32]
  int tid = threadIdx.x;
  int n0 = blockIdx.x * 128, m0 = blockIdx.y * 128;
  int wv = tid >> 6, lane = tid & 63, lanem = lane & 15, quad = lane >> 4;
  int wm = (wv >> 1) * 64, wn = (wv & 1) * 64;

  int rA = wv * 16 + (lane >> 2);
  int cc = (lane & 3) * 8;
  const u16* Ab = A + (size_t)(m0 + rA) * D_ + cc;
  const u16* Bb = Bw + (size_t)(n0 + rA) * D_ + cc;

  f32x4 acc[4][4];
#pragma unroll
  for (int mi = 0; mi < 4; ++mi)
#pragma unroll
    for (int ni = 0; ni < 4; ++ni)
      acc[mi][ni] = (f32x4){0.f, 0.f, 0.f, 0.f};

  for (int kt = 0; kt < 16; ++kt) {
    int k0 = kt * 64;
    __syncthreads();
#pragma unroll
    for (int ks = 0; ks < 2; ++ks)
#pragma unroll
      for (int j = 0; j < 2; ++j) {
        gl_lds16(Ab + k0 + ks * 32 + (size_t)j * 64 * D_,
                 &S[0][ks][(j * 256 + wv * 64) * 8]);
        gl_lds16(Bb + k0 + ks * 32 + (size_t)j * 64 * D_,
                 &S[1][ks][(j * 256 + wv * 64) * 8]);
      }
    __syncthreads();
#pragma unroll
    for (int ks = 0; ks < 2; ++ks) {
      bf16x8 af[4], bfr[4];
#pragma unroll
      for (int mi = 0; mi < 4; ++mi)
        af[mi] = ld8(&S[0][ks][(wm + mi * 16 + lanem) * 32 + quad * 8]);
#pragma unroll
      for (int ni = 0; ni < 4; ++ni)
        bfr[ni] = ld8(&S[1][ks][(wn + ni * 16 + lanem) * 32 + quad * 8]);
#pragma unroll
      for (int mi = 0; mi < 4; ++mi)
#pragma unroll
        for (int ni = 0; ni < 4; ++ni)
          acc[mi][ni] = __builtin_amdgcn_mfma_f32_16x16x32_bf16(af[mi], bfr[ni], acc[mi][ni], 0, 0, 0);
    }
  }

#pragma unroll
  for (int ni = 0; ni < 4; ++ni) {
    int gn = n0 + wn + ni * 16 + lanem;
    float bvv = bias[gn];
#pragma unroll
    for (int mi = 0; mi < 4; ++mi)
#pragma unroll
      for (int i = 0; i < 4; ++i) {
        int gm = m0 + wm + mi * 16 + quad * 4 + i;
        Co[(size_t)gm * D_ + gn] = acc[mi][ni][i] + bvv;
      }
  }
}

// Flash attention v4r2 (round-2 proven version, 67.8us).
__global__ __launch_bounds__(256, 4)
void flash4(const u16* __restrict__ qb, const u16* __restrict__ kb,
            const u16* __restrict__ vtb, u16* __restrict__ ob) {
  __shared__ u16 Ks[2][2][64][32];   // [buf][dhalf][slot][d32]  (slot = permuted key)
  __shared__ u16 Vs[2][2][64][32];   // [buf][shalf][hd][s32]
  int tid = threadIdx.x, wv = tid >> 6, lane = tid & 63;
  int lanem = lane & 15, quad = lane >> 4;
  int h = blockIdx.y, b = blockIdx.z;
  int z = (int)blockIdx.z;
  int qt = ((int)blockIdx.x ^ ((z & 1) * 15) ^ ((z >> 1) * 3)) & 15;
  size_t bh = (size_t)b * H_ + h;
  int qrow0 = qt * 128 + wv * 32;
  const u16* Qg = qb + (bh * T_ + qrow0) * HD_;
  const u16* Kg = kb + bh * T_ * HD_;
  const u16* Vg = vtb + bh * HD_ * T_;

  // staging: chunk tid -> slot=tid>>2, col8=tid&3; K source row is the permuted key
  int slot = tid >> 2, r = slot & 15;
  int key = (slot >> 5) * 32 + (r >> 2) * 8 + ((slot >> 4) & 1) * 4 + (r & 3);
  const u16* gK = Kg + (size_t)key * HD_ + (tid & 3) * 8;
  const u16* gV = Vg + (size_t)slot * T_ + (tid & 3) * 8;

  // Q as B-operand fragments (B[n=q=lanem][k=d=quad*8+j])
  bf16x8 bq[2][2];
#pragma unroll
  for (int mi = 0; mi < 2; ++mi)
#pragma unroll
    for (int ks = 0; ks < 2; ++ks)
      bq[mi][ks] = ld8(&Qg[(size_t)(mi * 16 + lanem) * HD_ + ks * 32 + quad * 8]);

  f32x4 acc_o[2][4];   // O^T[hd-tile ni][q], C layout
  float lsum[2][4];    // 4 independent partial sums per mi (dep-chain break)
#pragma unroll
  for (int mi = 0; mi < 2; ++mi) {
#pragma unroll
    for (int c = 0; c < 4; ++c) lsum[mi][c] = 0.f;
#pragma unroll
    for (int ni = 0; ni < 4; ++ni) acc_o[mi][ni] = (f32x4){0.f, 0.f, 0.f, 0.f};
  }

  int nIter = qt * 2 + 2;
  int myTiles = (qrow0 >> 6) + 1;

#define STAGE_KV(bufi, s0c)                                                 \
  do {                                                                      \
    gl_lds16(gK + (size_t)(s0c) * HD_,      &Ks[bufi][0][0][0] + wv * 512); \
    gl_lds16(gK + (size_t)(s0c) * HD_ + 32, &Ks[bufi][1][0][0] + wv * 512); \
    gl_lds16(gV + (s0c),                    &Vs[bufi][0][0][0] + wv * 512); \
    gl_lds16(gV + (s0c) + 32,               &Vs[bufi][1][0][0] + wv * 512); \
  } while (0)

  STAGE_KV(0, 0);
  for (int it = 0; it < nIter; ++it) {
    // hardened barrier: drain ALL outstanding memory ops (incl. the in-flight
    // global_load_lds prefetch) before the workgroup barrier.
    __builtin_amdgcn_s_waitcnt(0);
    __syncthreads();
    if (it + 1 < nIter) STAGE_KV((it + 1) & 1, (it + 1) * 64);
    if (it >= myTiles) continue;
    int s0 = it * 64, buf = it & 1;

    // S^T = K * Q^T : accs[mi][ni][i] = S[q=lanem][key = sl(ni,quad,i)]
    f32x4 accs[2][4];
#pragma unroll
    for (int mi = 0; mi < 2; ++mi)
#pragma unroll
      for (int ni = 0; ni < 4; ++ni) accs[mi][ni] = (f32x4){0.f, 0.f, 0.f, 0.f};
#pragma unroll
    for (int ks = 0; ks < 2; ++ks)
#pragma unroll
      for (int ni = 0; ni < 4; ++ni) {
        bf16x8 kf = ld8(&Ks[buf][ks][ni * 16 + lanem][quad * 8]);
        accs[0][ni] = __builtin_amdgcn_mfma_f32_16x16x32_bf16(kf, bq[0][ks], accs[0][ni], 0, 0, 0);
        accs[1][ni] = __builtin_amdgcn_mfma_f32_16x16x32_bf16(kf, bq[1][ks], accs[1][ni], 0, 0, 0);
      }

    // softmax (no-max, exp2; scale folded into Q): local key of accs[.][ni][i]
    // is sl = (ni>>1)*32 + quad*8 + (ni&1)*4 + i  (the staged permutation).
    // lsum partials indexed by i: four independent accumulation chains.
    if (s0 + 63 > qrow0) {
#pragma unroll
      for (int mi = 0; mi < 2; ++mi) {
        int qg = qrow0 + mi * 16 + lanem;
#pragma unroll
        for (int ni = 0; ni < 4; ++ni)
#pragma unroll
          for (int i = 0; i < 4; ++i) {
            int sl = (ni >> 1) * 32 + quad * 8 + (ni & 1) * 4 + i;
            float p = (s0 + sl > qg) ? 0.f : __builtin_amdgcn_exp2f(accs[mi][ni][i]);
            accs[mi][ni][i] = p;
            lsum[mi][i] += p;
          }
      }
    } else {
#pragma unroll
      for (int mi = 0; mi < 2; ++mi)
#pragma unroll
        for (int ni = 0; ni < 4; ++ni)
#pragma unroll
          for (int i = 0; i < 4; ++i) {
            float p = __builtin_amdgcn_exp2f(accs[mi][ni][i]);
            accs[mi][ni][i] = p;
            lsum[mi][i] += p;
          }
    }

    // pack: accs tiles (2c, 2c+1) -> PV B-frag for s-chunk c, directly in regs
#pragma unroll
    for (int c = 0; c < 2; ++c) {
      u32x4 pk0, pk1;
      pk0[0] = pkbf(accs[0][c * 2][0], accs[0][c * 2][1]);
      pk0[1] = pkbf(accs[0][c * 2][2], accs[0][c * 2][3]);
      pk0[2] = pkbf(accs[0][c * 2 + 1][0], accs[0][c * 2 + 1][1]);
      pk0[3] = pkbf(accs[0][c * 2 + 1][2], accs[0][c * 2 + 1][3]);
      pk1[0] = pkbf(accs[1][c * 2][0], accs[1][c * 2][1]);
      pk1[1] = pkbf(accs[1][c * 2][2], accs[1][c * 2][3]);
      pk1[2] = pkbf(accs[1][c * 2 + 1][0], accs[1][c * 2 + 1][1]);
      pk1[3] = pkbf(accs[1][c * 2 + 1][2], accs[1][c * 2 + 1][3]);
      bf16x8 bp0 = __builtin_bit_cast(bf16x8, pk0);
      bf16x8 bp1 = __builtin_bit_cast(bf16x8, pk1);
#pragma unroll
      for (int ni = 0; ni < 4; ++ni) {
        bf16x8 vf = ld8(&Vs[buf][c][ni * 16 + lanem][quad * 8]);
        acc_o[0][ni] = __builtin_amdgcn_mfma_f32_16x16x32_bf16(vf, bp0, acc_o[0][ni], 0, 0, 0);
        acc_o[1][ni] = __builtin_amdgcn_mfma_f32_16x16x32_bf16(vf, bp1, acc_o[1][ni], 0, 0, 0);
      }
    }
  }
#undef STAGE_KV

  // epilogue: O^T[hd=ni*16+quad*4+i][q=qrow0+mi*16+lanem] -> ob[q][h*64+hd]
#pragma unroll
  for (int mi = 0; mi < 2; ++mi) {
    float v = (lsum[mi][0] + lsum[mi][1]) + (lsum[mi][2] + lsum[mi][3]);
    v += __shfl_xor(v, 16);
    v += __shfl_xor(v, 32);
    float inv = 1.f / v;
    int q = qrow0 + mi * 16 + lanem;
    u16* og = ob + ((size_t)b * T_ + q) * D_ + h * HD_;
#pragma unroll
    for (int ni = 0; ni < 4; ++ni) {
      ushort4 st;
      st.x = f2bf(acc_o[mi][ni][0] * inv);
      st.y = f2bf(acc_o[mi][ni][1] * inv);
      st.z = f2bf(acc_o[mi][ni][2] * inv);
      st.w = f2bf(acc_o[mi][ni][3] * inv);
      *(ushort4*)(og + ni * 16 + quad * 4) = st;
    }
  }
}

extern "C" void kernel_launch(void* const* d_in, const int* in_sizes, int n_in,
                              void* d_out, int out_size, void* d_ws, size_t ws_size,
                              hipStream_t stream) {
  const float* x  = (const float*)d_in[0];
  const float* wq = (const float*)d_in[1];
  const float* bq = (const float*)d_in[2];
  const float* wk = (const float*)d_in[3];
  const float* bk = (const float*)d_in[4];
  const float* wv = (const float*)d_in[5];
  const float* bv = (const float*)d_in[6];
  const float* wo = (const float*)d_in[7];
  const float* bo = (const float*)d_in[8];

  char* ws = (char*)d_ws;
  const size_t MB = 1ull << 20;
  u16* xb   = (u16*)(ws + 0 * MB);   // [8192,1024] bf16
  u16* wqkv = (u16*)(ws + 16 * MB);  // [3072,1024] bf16 (wq|wk|wv contiguous)
  u16* wob  = (u16*)(ws + 22 * MB);
  u16* qb   = (u16*)(ws + 24 * MB);  // [B,H,T,HD] bf16 (pre-scaled QSCALE)
  u16* kb   = (u16*)(ws + 40 * MB);  // [B,H,T,HD]
  u16* vtb  = (u16*)(ws + 56 * MB);  // [B,H,HD,T]
  u16* ob   = (u16*)(ws + 72 * MB);  // [8192,1024] bf16

  cvt_all<<<(M_ * D_ + 4 * D_ * D_) / 1024, 256, 0, stream>>>(
      x, wq, wk, wv, wo, xb, wqkv, wqkv + (size_t)D_ * D_, wqkv + 2 * (size_t)D_ * D_, wob);

  gemm_qkv<<<768, 512, 0, stream>>>(xb, wqkv, bq, bk, bv, qb, kb, vtb);

  flash4<<<dim3(T_ / 128, H_, B_), 256, 0, stream>>>(qb, kb, vtb, ob);

  gemm_wo<<<dim3(D_ / 128, M_ / 128), 256, 0, stream>>>(ob, wob, bo, (float*)d_out);
}

// Round 6
// 257.948 us; speedup vs baseline: 1.0449x; 1.0157x over previous
//
#include <hip/hip_runtime.h>
#include <cstdint>

typedef __bf16 bf16x8 __attribute__((ext_vector_type(8)));
typedef float f32x4 __attribute__((ext_vector_type(4)));
typedef uint32_t u32x4 __attribute__((ext_vector_type(4)));
typedef unsigned short u16;

#define B_ 4
#define T_ 2048
#define D_ 1024
#define H_ 16
#define HD_ 64
#define M_ (B_*T_)
// attention scale 1/8 with log2(e) folded in, applied in Q epilogue -> softmax uses exp2
#define QSCALE 0.1803368801111204f

__device__ __forceinline__ u16 f2bf(float f) {
  union { float f; uint32_t u; } x; x.f = f;
  uint32_t u = x.u;
  uint32_t r = (u + 0x7FFFu + ((u >> 16) & 1u)) >> 16;
  return (u16)r;
}

// fast pack: 2 fp32 -> packed bf16x2 via v_perm_b32 (2 adds + 1 perm); p>=0 here.
__device__ __forceinline__ uint32_t pkbf(float a, float b) {
  union { float f; uint32_t u; } x, y; x.f = a; y.f = b;
  uint32_t t0 = x.u + 0x8000u, t1 = y.u + 0x8000u;
  return __builtin_amdgcn_perm(t1, t0, 0x07060302u);  // [t0.b2,t0.b3,t1.b2,t1.b3]
}

__device__ __forceinline__ bf16x8 ld8(const u16* p) {
  return *(const bf16x8*)p;
}

// async global->LDS, 16B per lane; lds ptr must be wave-uniform base (HW adds lane*16)
__device__ __forceinline__ void gl_lds16(const u16* g, u16* l) {
  __builtin_amdgcn_global_load_lds(
      (__attribute__((address_space(1))) void*)(g),
      (__attribute__((address_space(3))) void*)(l), 16, 0, 0);
}

// Fused fp32->bf16 convert of x + 4 weight matrices.
__global__ void cvt_all(const float* __restrict__ x, const float* __restrict__ wq,
                        const float* __restrict__ wk, const float* __restrict__ wv,
                        const float* __restrict__ wo,
                        u16* __restrict__ xb, u16* __restrict__ wqb, u16* __restrict__ wkb,
                        u16* __restrict__ wvb, u16* __restrict__ wob) {
  const long NX = (long)M_ * D_;
  long i = ((long)blockIdx.x * 256 + threadIdx.x) * 4;
  const float* s; u16* d; long j;
  if (i < NX) { s = x; d = xb; j = i; }
  else {
    long r = i - NX; int seg = (int)(r >> 20); j = r & ((1 << 20) - 1);
    s = seg == 0 ? wq : seg == 1 ? wk : seg == 2 ? wv : wo;
    d = seg == 0 ? wqb : seg == 1 ? wkb : seg == 2 ? wvb : wob;
  }
  float4 v = *(const float4*)(s + j);
  ushort4 o;
  o.x = f2bf(v.x); o.y = f2bf(v.y); o.z = f2bf(v.z); o.w = f2bf(v.w);
  *(ushort4*)(d + j) = o;
}

// ---------------------------------------------------------------------------
// v3 GEMM structure (round-2, replay-green, 67.8us on qkv = 760 TF):
//   256x128 tile, 512 thr = 8 waves (4M x 2N), per-wave 64x64 (acc[4][4]).
//   LDS triple buffer [3][384][64] (A rows 0..255 | B rows 256..383), 144 KiB.
//   Per K-tile: 2 phases (mi-halves); ph0 = 12 ds_read + 3 stage units,
//   ph1 = 4 ds_read + 3 stage units; full lgkmcnt(0) drain before each MFMA
//   (counted-lgkm pipelining measured SLOWER: 71.0 vs 67.8 — reverted);
//   counted vmcnt(6) once per tile; stage(kt+2) -> p2 (trivially-safe WAR).
//   T2 swizzle via pre-swizzled global source; XCD-chunked grid swizzle.
//   Round-5 A/B: v4 counted-lgkm = 71.0us, v3 drain = 67.8us. v3 wins.
// ---------------------------------------------------------------------------

template <int PH>
__device__ __forceinline__ void ldA_ph(bf16x8 (&af)[2][2], const u16* buf,
                                       int wr, int lanem, int quad) {
#pragma unroll
  for (int mi = 0; mi < 2; ++mi)
#pragma unroll
    for (int ks = 0; ks < 2; ++ks) {
      int row = wr * 64 + (PH * 2 + mi) * 16 + lanem;
      int off = row * 64 + ((ks * 32 + quad * 8) ^ ((lanem & 7) << 3));  // u16 units
      af[mi][ks] = ld8(buf + off);
    }
}

__device__ __forceinline__ void ldB_all(bf16x8 (&bfr)[4][2], const u16* buf,
                                        int wc, int lanem, int quad) {
#pragma unroll
  for (int nj = 0; nj < 4; ++nj)
#pragma unroll
    for (int ks = 0; ks < 2; ++ks) {
      int row = 256 + wc * 64 + nj * 16 + lanem;
      int off = row * 64 + ((ks * 32 + quad * 8) ^ ((lanem & 7) << 3));
      bfr[nj][ks] = ld8(buf + off);
    }
}

template <int PH>
__device__ __forceinline__ void mfmaPH(f32x4 (&acc)[4][4], const bf16x8 (&af)[2][2],
                                       const bf16x8 (&bfr)[4][2]) {
#pragma unroll
  for (int mi = 0; mi < 2; ++mi)
#pragma unroll
    for (int nj = 0; nj < 4; ++nj)
#pragma unroll
      for (int ks = 0; ks < 2; ++ks)
        acc[PH * 2 + mi][nj] = __builtin_amdgcn_mfma_f32_16x16x32_bf16(
            af[mi][ks], bfr[nj][ks], acc[PH * 2 + mi][nj], 0, 0, 0);
}

#define PH_PRE()                                        \
  __builtin_amdgcn_s_barrier();                         \
  asm volatile("s_waitcnt lgkmcnt(0)" ::: "memory");    \
  __builtin_amdgcn_sched_barrier(0);                    \
  __builtin_amdgcn_s_setprio(1)

#define PH_POST()                                       \
  __builtin_amdgcn_s_setprio(0);                        \
  __builtin_amdgcn_s_barrier()

// v3 K-loop over 16 tiles; needs in scope: sm.S, m0, n0, wv, wr, wc, lane geom,
// grow/gcol, acc, af, bfr. Asrc rows = A-panel (256), Bsrc rows = B-panel (128).
#define GEMM_V3_KLOOP(Asrc, Bsrc)                                              \
  u16* p0 = &sm.S[0][0][0];                                                    \
  u16* p1 = &sm.S[1][0][0];                                                    \
  u16* p2 = &sm.S[2][0][0];                                                    \
  auto stage = [&](u16* bufbase, int u, int k0) {                              \
    const u16* src = (u < 4)                                                   \
        ? Asrc + (size_t)(m0 + u * 64 + wv * 8 + grow) * D_ + k0 + gcol        \
        : Bsrc + (size_t)(n0 + (u - 4) * 64 + wv * 8 + grow) * D_ + k0 + gcol; \
    gl_lds16(src, bufbase + (u * 64 + wv * 8) * 64);                           \
  };                                                                           \
  _Pragma("unroll")                                                            \
  for (int u = 0; u < 6; ++u) stage(p0, u, 0);                                 \
  _Pragma("unroll")                                                            \
  for (int u = 0; u < 6; ++u) stage(p1, u, 64);                                \
  asm volatile("s_waitcnt vmcnt(6)" ::: "memory");                             \
  __builtin_amdgcn_s_barrier();                                                \
  for (int kt = 0; kt < 16; ++kt) {                                            \
    const int k2 = (kt + 2) << 6;                                              \
    ldA_ph<0>(af, p0, wr, lanem, quad);                                        \
    ldB_all(bfr, p0, wc, lanem, quad);                                         \
    if (kt < 14) { stage(p2, 0, k2); stage(p2, 1, k2); stage(p2, 2, k2); }     \
    PH_PRE();                                                                  \
    mfmaPH<0>(acc, af, bfr);                                                   \
    PH_POST();                                                                 \
    ldA_ph<1>(af, p0, wr, lanem, quad);                                        \
    if (kt < 14) { stage(p2, 3, k2); stage(p2, 4, k2); stage(p2, 5, k2); }     \
    __builtin_amdgcn_s_barrier();                                              \
    asm volatile("s_waitcnt lgkmcnt(0)" ::: "memory");                         \
    __builtin_amdgcn_sched_barrier(0);                                         \
    __builtin_amdgcn_s_setprio(1);                                             \
    mfmaPH<1>(acc, af, bfr);                                                   \
    __builtin_amdgcn_s_setprio(0);                                             \
    if (kt < 14)       asm volatile("s_waitcnt vmcnt(6)" ::: "memory");        \
    else if (kt == 14) asm volatile("s_waitcnt vmcnt(0)" ::: "memory");        \
    __builtin_amdgcn_s_barrier();                                              \
    u16* t = p0; p0 = p1; p1 = p2; p2 = t;                                     \
  }

__global__ __launch_bounds__(512, 2)
void gemm_qkv(const u16* __restrict__ A, const u16* __restrict__ Bw,
              const float* __restrict__ bq, const float* __restrict__ bk,
              const float* __restrict__ bv,
              u16* __restrict__ qb, u16* __restrict__ kb, u16* __restrict__ vtb) {
  __shared__ union {
    u16 S[3][384][64];   // 3 bufs x (A rows 0..255 | B rows 256..383) x 64k = 144 KiB
    u16 C[256 * 136];    // epilogue bounce: Q/K [256][136]; V uses [128][264]
  } sm;

  const int tid = threadIdx.x;
  const int wv = tid >> 6, lane = tid & 63;
  const int lanem = lane & 15, quad = lane >> 4;
  const int wr = wv >> 1, wc = wv & 1;   // wave grid 4 (M) x 2 (N)

  // XCD-chunked bijective swizzle: 96 consecutive tiles (= 4 m-rows) per XCD
  const int l = ((int)blockIdx.x & 7) * 96 + ((int)blockIdx.x >> 3);
  const int n0 = (l % 24) * 128, m0 = (l / 24) * 256;

  // per-lane pre-swizzled global source (T2 involution, row&7 == grow)
  const int grow = lane >> 3;
  const int gcol = (((lane & 7) ^ grow) * 8);

  f32x4 acc[4][4];
#pragma unroll
  for (int a = 0; a < 4; ++a)
#pragma unroll
    for (int b = 0; b < 4; ++b) acc[a][b] = (f32x4){0.f, 0.f, 0.f, 0.f};

  bf16x8 af[2][2];
  bf16x8 bfr[4][2];

  GEMM_V3_KLOOP(A, Bw);

  // ---- epilogue: bounce through the (now free) LDS union
  const int seg = n0 >> 10, n0l = n0 & 1023;   // BN=128 divides 1024: no crossing
  const int bb = m0 >> 11, tl0 = m0 & (T_ - 1);

  if (seg == 2) {
    // V: transposed bounce [128 ncol][264 (256 t + pad)], single pass
    __syncthreads();
#pragma unroll
    for (int a = 0; a < 4; ++a)
#pragma unroll
      for (int nj = 0; nj < 4; ++nj) {
        int ncol = wc * 64 + nj * 16 + lanem;
        float bvv = bv[n0l + ncol];
        int mb = wr * 64 + a * 16 + quad * 4;
        ushort4 w4;
        w4.x = f2bf(acc[a][nj][0] + bvv);
        w4.y = f2bf(acc[a][nj][1] + bvv);
        w4.z = f2bf(acc[a][nj][2] + bvv);
        w4.w = f2bf(acc[a][nj][3] + bvv);
        *(ushort4*)&sm.C[ncol * 264 + mb] = w4;
      }
    __syncthreads();
#pragma unroll
    for (int it = 0; it < 8; ++it) {
      int chunk = it * 512 + tid;
      int nrow = chunk >> 5, c8 = chunk & 31;
      int gnl = n0l + nrow;
      int hh = gnl >> 6, hd = gnl & 63;
      *(uint4*)&vtb[(((size_t)bb * H_ + hh) * HD_ + hd) * T_ + tl0 + c8 * 8] =
          *(const uint4*)&sm.C[nrow * 264 + c8 * 8];
    }
  } else {
    // Q/K: [256 t][136 (128 hd-cols + pad)] bounce, single pass
    const float* bias = seg == 0 ? bq : bk;
    u16* out = seg == 0 ? qb : kb;
    const float sc = seg == 0 ? QSCALE : 1.0f;
    __syncthreads();
#pragma unroll
    for (int a = 0; a < 4; ++a)
#pragma unroll
      for (int nj = 0; nj < 4; ++nj) {
        int col = wc * 64 + nj * 16 + lanem;
        float bvv = bias[n0l + col];
        int r = wr * 64 + a * 16 + quad * 4;
#pragma unroll
        for (int i = 0; i < 4; ++i)
          sm.C[(r + i) * 136 + col] = f2bf((acc[a][nj][i] + bvv) * sc);
      }
    __syncthreads();
#pragma unroll
    for (int it = 0; it < 8; ++it) {
      int chunk = it * 512 + tid;
      int row = chunk >> 4, c8 = chunk & 15;
      int col0 = c8 * 8;
      int hh = (n0l + col0) >> 6, hd = col0 & 63;
      int t = tl0 + row;
      *(uint4*)&out[(((size_t)bb * H_ + hh) * T_ + t) * HD_ + hd] =
          *(const uint4*)&sm.C[row * 136 + col0];
    }
  }
}

// Output projection v3-port: same replay-green v3 K-loop structure as gemm_qkv,
// 256x128 tile. Grid 8(N) x 32(M) = 256 blocks = 1 uniform round (1 block/CU).
// Epilogue: direct fp32 stores from registers (no LDS reuse after the final
// drained barrier -> no new WAR surface vs the raced round-4 counted-lgkm v2).
__global__ __launch_bounds__(512, 2)
void gemm_wo(const u16* __restrict__ A, const u16* __restrict__ Bw,
             const float* __restrict__ bias, float* __restrict__ Co) {
  __shared__ union {
    u16 S[3][384][64];
    u16 C[256 * 136];
  } sm;

  const int tid = threadIdx.x;
  const int wv = tid >> 6, lane = tid & 63;
  const int lanem = lane & 15, quad = lane >> 4;
  const int wr = wv >> 1, wc = wv & 1;

  // XCD-chunked swizzle: 32 consecutive tiles (= 4 m-rows of 8 n-cols) per XCD
  const int l = ((int)blockIdx.x & 7) * 32 + ((int)blockIdx.x >> 3);
  const int n0 = (l & 7) * 128, m0 = (l >> 3) * 256;

  const int grow = lane >> 3;
  const int gcol = (((lane & 7) ^ grow) * 8);

  f32x4 acc[4][4];
#pragma unroll
  for (int a = 0; a < 4; ++a)
#pragma unroll
    for (int b = 0; b < 4; ++b) acc[a][b] = (f32x4){0.f, 0.f, 0.f, 0.f};

  bf16x8 af[2][2];
  bf16x8 bfr[4][2];

  GEMM_V3_KLOOP(A, Bw);

  // direct fp32 epilogue: col = n0+wc*64+nj*16+lanem, row = m0+wr*64+a*16+quad*4+i
#pragma unroll
  for (int nj = 0; nj < 4; ++nj) {
    int gn = n0 + wc * 64 + nj * 16 + lanem;
    float bvv = bias[gn];
#pragma unroll
    for (int a = 0; a < 4; ++a)
#pragma unroll
      for (int i = 0; i < 4; ++i) {
        int gm = m0 + wr * 64 + a * 16 + quad * 4 + i;
        Co[(size_t)gm * D_ + gn] = acc[a][nj][i] + bvv;
      }
  }
}

// Flash attention v4r2 (round-2 proven version, 67.8us).
__global__ __launch_bounds__(256, 4)
void flash4(const u16* __restrict__ qb, const u16* __restrict__ kb,
            const u16* __restrict__ vtb, u16* __restrict__ ob) {
  __shared__ u16 Ks[2][2][64][32];   // [buf][dhalf][slot][d32]  (slot = permuted key)
  __shared__ u16 Vs[2][2][64][32];   // [buf][shalf][hd][s32]
  int tid = threadIdx.x, wv = tid >> 6, lane = tid & 63;
  int lanem = lane & 15, quad = lane >> 4;
  int h = blockIdx.y, b = blockIdx.z;
  int z = (int)blockIdx.z;
  int qt = ((int)blockIdx.x ^ ((z & 1) * 15) ^ ((z >> 1) * 3)) & 15;
  size_t bh = (size_t)b * H_ + h;
  int qrow0 = qt * 128 + wv * 32;
  const u16* Qg = qb + (bh * T_ + qrow0) * HD_;
  const u16* Kg = kb + bh * T_ * HD_;
  const u16* Vg = vtb + bh * HD_ * T_;

  // staging: chunk tid -> slot=tid>>2, col8=tid&3; K source row is the permuted key
  int slot = tid >> 2, r = slot & 15;
  int key = (slot >> 5) * 32 + (r >> 2) * 8 + ((slot >> 4) & 1) * 4 + (r & 3);
  const u16* gK = Kg + (size_t)key * HD_ + (tid & 3) * 8;
  const u16* gV = Vg + (size_t)slot * T_ + (tid & 3) * 8;

  // Q as B-operand fragments (B[n=q=lanem][k=d=quad*8+j])
  bf16x8 bq[2][2];
#pragma unroll
  for (int mi = 0; mi < 2; ++mi)
#pragma unroll
    for (int ks = 0; ks < 2; ++ks)
      bq[mi][ks] = ld8(&Qg[(size_t)(mi * 16 + lanem) * HD_ + ks * 32 + quad * 8]);

  f32x4 acc_o[2][4];   // O^T[hd-tile ni][q], C layout
  float lsum[2][4];    // 4 independent partial sums per mi (dep-chain break)
#pragma unroll
  for (int mi = 0; mi < 2; ++mi) {
#pragma unroll
    for (int c = 0; c < 4; ++c) lsum[mi][c] = 0.f;
#pragma unroll
    for (int ni = 0; ni < 4; ++ni) acc_o[mi][ni] = (f32x4){0.f, 0.f, 0.f, 0.f};
  }

  int nIter = qt * 2 + 2;
  int myTiles = (qrow0 >> 6) + 1;

#define STAGE_KV(bufi, s0c)                                                 \
  do {                                                                      \
    gl_lds16(gK + (size_t)(s0c) * HD_,      &Ks[bufi][0][0][0] + wv * 512); \
    gl_lds16(gK + (size_t)(s0c) * HD_ + 32, &Ks[bufi][1][0][0] + wv * 512); \
    gl_lds16(gV + (s0c),                    &Vs[bufi][0][0][0] + wv * 512); \
    gl_lds16(gV + (s0c) + 32,               &Vs[bufi][1][0][0] + wv * 512); \
  } while (0)

  STAGE_KV(0, 0);
  for (int it = 0; it < nIter; ++it) {
    // hardened barrier: drain ALL outstanding memory ops (incl. the in-flight
    // global_load_lds prefetch) before the workgroup barrier.
    __builtin_amdgcn_s_waitcnt(0);
    __syncthreads();
    if (it + 1 < nIter) STAGE_KV((it + 1) & 1, (it + 1) * 64);
    if (it >= myTiles) continue;
    int s0 = it * 64, buf = it & 1;

    // S^T = K * Q^T : accs[mi][ni][i] = S[q=lanem][key = sl(ni,quad,i)]
    f32x4 accs[2][4];
#pragma unroll
    for (int mi = 0; mi < 2; ++mi)
#pragma unroll
      for (int ni = 0; ni < 4; ++ni) accs[mi][ni] = (f32x4){0.f, 0.f, 0.f, 0.f};
#pragma unroll
    for (int ks = 0; ks < 2; ++ks)
#pragma unroll
      for (int ni = 0; ni < 4; ++ni) {
        bf16x8 kf = ld8(&Ks[buf][ks][ni * 16 + lanem][quad * 8]);
        accs[0][ni] = __builtin_amdgcn_mfma_f32_16x16x32_bf16(kf, bq[0][ks], accs[0][ni], 0, 0, 0);
        accs[1][ni] = __builtin_amdgcn_mfma_f32_16x16x32_bf16(kf, bq[1][ks], accs[1][ni], 0, 0, 0);
      }

    // softmax (no-max, exp2; scale folded into Q): local key of accs[.][ni][i]
    // is sl = (ni>>1)*32 + quad*8 + (ni&1)*4 + i  (the staged permutation).
    // lsum partials indexed by i: four independent accumulation chains.
    if (s0 + 63 > qrow0) {
#pragma unroll
      for (int mi = 0; mi < 2; ++mi) {
        int qg = qrow0 + mi * 16 + lanem;
#pragma unroll
        for (int ni = 0; ni < 4; ++ni)
#pragma unroll
          for (int i = 0; i < 4; ++i) {
            int sl = (ni >> 1) * 32 + quad * 8 + (ni & 1) * 4 + i;
            float p = (s0 + sl > qg) ? 0.f : __builtin_amdgcn_exp2f(accs[mi][ni][i]);
            accs[mi][ni][i] = p;
            lsum[mi][i] += p;
          }
      }
    } else {
#pragma unroll
      for (int mi = 0; mi < 2; ++mi)
#pragma unroll
        for (int ni = 0; ni < 4; ++ni)
#pragma unroll
          for (int i = 0; i < 4; ++i) {
            float p = __builtin_amdgcn_exp2f(accs[mi][ni][i]);
            accs[mi][ni][i] = p;
            lsum[mi][i] += p;
          }
    }

    // pack: accs tiles (2c, 2c+1) -> PV B-frag for s-chunk c, directly in regs
#pragma unroll
    for (int c = 0; c < 2; ++c) {
      u32x4 pk0, pk1;
      pk0[0] = pkbf(accs[0][c * 2][0], accs[0][c * 2][1]);
      pk0[1] = pkbf(accs[0][c * 2][2], accs[0][c * 2][3]);
      pk0[2] = pkbf(accs[0][c * 2 + 1][0], accs[0][c * 2 + 1][1]);
      pk0[3] = pkbf(accs[0][c * 2 + 1][2], accs[0][c * 2 + 1][3]);
      pk1[0] = pkbf(accs[1][c * 2][0], accs[1][c * 2][1]);
      pk1[1] = pkbf(accs[1][c * 2][2], accs[1][c * 2][3]);
      pk1[2] = pkbf(accs[1][c * 2 + 1][0], accs[1][c * 2 + 1][1]);
      pk1[3] = pkbf(accs[1][c * 2 + 1][2], accs[1][c * 2 + 1][3]);
      bf16x8 bp0 = __builtin_bit_cast(bf16x8, pk0);
      bf16x8 bp1 = __builtin_bit_cast(bf16x8, pk1);
#pragma unroll
      for (int ni = 0; ni < 4; ++ni) {
        bf16x8 vf = ld8(&Vs[buf][c][ni * 16 + lanem][quad * 8]);
        acc_o[0][ni] = __builtin_amdgcn_mfma_f32_16x16x32_bf16(vf, bp0, acc_o[0][ni], 0, 0, 0);
        acc_o[1][ni] = __builtin_amdgcn_mfma_f32_16x16x32_bf16(vf, bp1, acc_o[1][ni], 0, 0, 0);
      }
    }
  }
#undef STAGE_KV

  // epilogue: O^T[hd=ni*16+quad*4+i][q=qrow0+mi*16+lanem] -> ob[q][h*64+hd]
#pragma unroll
  for (int mi = 0; mi < 2; ++mi) {
    float v = (lsum[mi][0] + lsum[mi][1]) + (lsum[mi][2] + lsum[mi][3]);
    v += __shfl_xor(v, 16);
    v += __shfl_xor(v, 32);
    float inv = 1.f / v;
    int q = qrow0 + mi * 16 + lanem;
    u16* og = ob + ((size_t)b * T_ + q) * D_ + h * HD_;
#pragma unroll
    for (int ni = 0; ni < 4; ++ni) {
      ushort4 st;
      st.x = f2bf(acc_o[mi][ni][0] * inv);
      st.y = f2bf(acc_o[mi][ni][1] * inv);
      st.z = f2bf(acc_o[mi][ni][2] * inv);
      st.w = f2bf(acc_o[mi][ni][3] * inv);
      *(ushort4*)(og + ni * 16 + quad * 4) = st;
    }
  }
}

extern "C" void kernel_launch(void* const* d_in, const int* in_sizes, int n_in,
                              void* d_out, int out_size, void* d_ws, size_t ws_size,
                              hipStream_t stream) {
  const float* x  = (const float*)d_in[0];
  const float* wq = (const float*)d_in[1];
  const float* bq = (const float*)d_in[2];
  const float* wk = (const float*)d_in[3];
  const float* bk = (const float*)d_in[4];
  const float* wv = (const float*)d_in[5];
  const float* bv = (const float*)d_in[6];
  const float* wo = (const float*)d_in[7];
  const float* bo = (const float*)d_in[8];

  char* ws = (char*)d_ws;
  const size_t MB = 1ull << 20;
  u16* xb   = (u16*)(ws + 0 * MB);   // [8192,1024] bf16
  u16* wqkv = (u16*)(ws + 16 * MB);  // [3072,1024] bf16 (wq|wk|wv contiguous)
  u16* wob  = (u16*)(ws + 22 * MB);
  u16* qb   = (u16*)(ws + 24 * MB);  // [B,H,T,HD] bf16 (pre-scaled QSCALE)
  u16* kb   = (u16*)(ws + 40 * MB);  // [B,H,T,HD]
  u16* vtb  = (u16*)(ws + 56 * MB);  // [B,H,HD,T]
  u16* ob   = (u16*)(ws + 72 * MB);  // [8192,1024] bf16

  cvt_all<<<(M_ * D_ + 4 * D_ * D_) / 1024, 256, 0, stream>>>(
      x, wq, wk, wv, wo, xb, wqkv, wqkv + (size_t)D_ * D_, wqkv + 2 * (size_t)D_ * D_, wob);

  gemm_qkv<<<768, 512, 0, stream>>>(xb, wqkv, bq, bk, bv, qb, kb, vtb);

  flash4<<<dim3(T_ / 128, H_, B_), 256, 0, stream>>>(qb, kb, vtb, ob);

  gemm_wo<<<256, 512, 0, stream>>>(ob, wob, bo, (float*)d_out);
}